// Round 11
// baseline (520.269 us; speedup 1.0000x reference)
//
#include <hip/hip_runtime.h>
#include <math.h>

#define NB 46
#define NS 50
#define ND 768
#define GAMA 0.96875f
#define NM 2300   // NB*NS rows
#define HALFC 384 // cols per recur block
#define SROW 384  // S panel row stride (floats)

using bfrag  = __attribute__((ext_vector_type(8))) short;   // 8 bf16 = 4 VGPRs
using f32x16 = __attribute__((ext_vector_type(16))) float;  // 32x32 acc

union FragU { unsigned u[4]; bfrag f; };

// ---------------- Kernel 1: QKV projections (+bias, +pe for Q,K) ----------
__global__ __launch_bounds__(256) void qkv_gemm(
    const float* __restrict__ text_emb, const float* __restrict__ emb,
    const float* __restrict__ Wq, const float* __restrict__ bq,
    const float* __restrict__ Wk, const float* __restrict__ bk,
    const float* __restrict__ Wv, const float* __restrict__ bv,
    float* __restrict__ Q, float* __restrict__ K, float* __restrict__ V)
{
    const int z = blockIdx.z;
    const float* X    = (z == 0) ? text_emb : emb;
    const float* W    = (z == 0) ? Wq : (z == 1) ? Wk : Wv;
    const float* bias = (z == 0) ? bq : (z == 1) ? bk : bv;
    float* out        = (z == 0) ? Q  : (z == 1) ? K  : V;

    __shared__ float Xs[16][68];
    __shared__ float Ws[16][68];

    const int tid = threadIdx.x;
    const int tx = tid & 15, ty = tid >> 4;
    const int m0 = blockIdx.x * 64, n0 = blockIdx.y * 64;

    const int lrow = tid >> 2;        // 0..63
    const int lk   = (tid & 3) * 4;   // 0,4,8,12

    float acc[4][4];
    #pragma unroll
    for (int i = 0; i < 4; i++)
        #pragma unroll
        for (int j = 0; j < 4; j++) acc[i][j] = 0.f;

    for (int k0 = 0; k0 < ND; k0 += 16) {
        float4 xv = make_float4(0.f, 0.f, 0.f, 0.f);
        const int xm = m0 + lrow;
        if (xm < NM) xv = *reinterpret_cast<const float4*>(&X[xm * ND + k0 + lk]);
        const float4 wv = *reinterpret_cast<const float4*>(&W[(n0 + lrow) * ND + k0 + lk]);
        Xs[lk + 0][lrow] = xv.x; Xs[lk + 1][lrow] = xv.y;
        Xs[lk + 2][lrow] = xv.z; Xs[lk + 3][lrow] = xv.w;
        Ws[lk + 0][lrow] = wv.x; Ws[lk + 1][lrow] = wv.y;
        Ws[lk + 2][lrow] = wv.z; Ws[lk + 3][lrow] = wv.w;
        __syncthreads();
        #pragma unroll
        for (int k = 0; k < 16; k++) {
            const float4 a  = *reinterpret_cast<const float4*>(&Xs[k][4 * ty]);
            const float4 b4 = *reinterpret_cast<const float4*>(&Ws[k][4 * tx]);
            const float av[4]  = {a.x,  a.y,  a.z,  a.w};
            const float bv4[4] = {b4.x, b4.y, b4.z, b4.w};
            #pragma unroll
            for (int i = 0; i < 4; i++)
                #pragma unroll
                for (int j = 0; j < 4; j++) acc[i][j] += av[i] * bv4[j];
        }
        __syncthreads();
    }

    const float C2 = -0.0239861701969175f; // -2*ln(10000)/768
    #pragma unroll
    for (int i = 0; i < 4; i++) {
        const int m = m0 + 4 * ty + i;
        if (m >= NM) continue;
        const int bpos = m / NS;  // pe indexed by BATCH position (faithful to source)
        #pragma unroll
        for (int j = 0; j < 4; j++) {
            const int n = n0 + 4 * tx + j;
            float v = acc[i][j] + bias[n];
            if (z < 2) {
                const int h = n >> 1;
                const float ang = (float)bpos * expf((float)h * C2);
                v += (n & 1) ? cosf(ang) : sinf(ang);
            }
            out[m * ND + n] = v;
        }
    }
}

// ---------------- Kernel 2: scores+softmax+ctx, and Ag = gamma*Q_trans -----
__global__ __launch_bounds__(64) void attn(
    const float* __restrict__ Q, const float* __restrict__ K,
    const float* __restrict__ V,
    const float* __restrict__ lin_w, const float* __restrict__ lin_b,
    float* __restrict__ Ag, float* __restrict__ ctx_out)
{
    const int bq = blockIdx.x;
    const int b = bq / NS, q = bq % NS;
    const int lane = threadIdx.x;

    const float* Qr = Q + (b * NS + q) * ND;
    float qv[12];
    #pragma unroll
    for (int m = 0; m < 12; m++) qv[m] = Qr[m * 64 + lane];

    // scores: lane k ends up holding score[k]*8
    float mysc = 0.f;
    for (int k = 0; k < NS; k++) {
        const float* Kr = K + (b * NS + k) * ND;
        float s = 0.f;
        #pragma unroll
        for (int m = 0; m < 12; m++) s += qv[m] * Kr[m * 64 + lane];
        #pragma unroll
        for (int off = 32; off; off >>= 1) s += __shfl_xor(s, off);
        if (lane == k) mysc = s * 8.f;
    }
    // Q_trans row q: lane j holds Qt[j]; write Ag = gamma*(Qt + lin_b)
    float myqt = 0.f;
    for (int j = 0; j < NS; j++) {
        const float* Lr = lin_w + j * ND;
        float s = 0.f;
        #pragma unroll
        for (int m = 0; m < 12; m++) s += qv[m] * Lr[m * 64 + lane];
        #pragma unroll
        for (int off = 32; off; off >>= 1) s += __shfl_xor(s, off);
        if (lane == j) myqt = s;
    }
    if (lane < NS)
        Ag[b * (NS * NS) + q * NS + lane] = GAMA * (myqt + lin_b[lane]);

    // softmax over lanes 0..49
    const float sc = (lane < NS) ? mysc : -INFINITY;
    float mx = sc;
    #pragma unroll
    for (int off = 32; off; off >>= 1) mx = fmaxf(mx, __shfl_xor(mx, off));
    const float e = (lane < NS) ? expf(sc - mx) : 0.f;
    float sum = e;
    #pragma unroll
    for (int off = 32; off; off >>= 1) sum += __shfl_xor(sum, off);
    const float p = e / sum;

    // ctx row = sum_k p_k * V[b,k,:]
    float acc[12];
    #pragma unroll
    for (int m = 0; m < 12; m++) acc[m] = 0.f;
    for (int k = 0; k < NS; k++) {
        const float pk = __shfl(p, k);
        const float* Vr = V + (b * NS + k) * ND;
        #pragma unroll
        for (int m = 0; m < 12; m++) acc[m] += pk * Vr[m * 64 + lane];
    }
    float* Cr = ctx_out + (b * NS + q) * ND;
    #pragma unroll
    for (int m = 0; m < 12; m++) Cr[m * 64 + lane] = acc[m];
}

// ---------------- Kernel 3: gamma-decay recurrence via MFMA ----------------
// rec[i,b,:,:] = Ag_b @ rec[i-1,b,:,:] + ctx[i], padded 50->64 on M,K.
// R10 lesson: 1104 waves each writing 128B segments at 3KB stride ran at
// 1.4 TB/s (DRAM row-activate bound, ~22% of achievable; NT vs plain stores
// identical -> pattern, not ack path). Fix: block = (b, 384-col half),
// 92 blocks x 6 waves (64 cols each). State round-trips through a ping-pong
// LDS panel S[2][50x384] (150 KB); rec[i-1] is written by a COOPERATIVE flat
// float4 sweep over the staged panel (1.5 KB/row contiguous, rows in order)
// -> 92 sequential write streams instead of 1104 scattered ones.
// A in bf16 hi/lo MFMA fragments loaded once (R9); B-frags packed on the fly
// from staged f32 (bitwise-identical to R9's P path). One lgkm-only barrier
// per step (R6/R7); acc loads issue before the iter's stores (vm FIFO, R6).
__global__ __launch_bounds__(384, 1) void recur(
    const float* __restrict__ Ag, const float* __restrict__ ctx,
    float* __restrict__ rec)
{
    const int blk  = blockIdx.x;        // 0..91
    const int b    = blk >> 1;
    const int half = blk & 1;
    const int tid  = threadIdx.x;       // 0..383
    const int w    = tid >> 6;          // wave 0..5
    const int l    = tid & 63;
    const int c    = l & 31;
    const int h    = l >> 5;
    const int colbase = half * HALFC;

    __shared__ float S[2][NS * SROW];   // ping-pong state panels, 2 x 75 KB

    // ---- A fragments (hi/lo), ONCE, straight from global (R9 verbatim) ----
    const float* __restrict__ Ab = Ag + b * (NS * NS);
    bfrag Ah[2][4], Al[2][4];
    #pragma unroll
    for (int mt = 0; mt < 2; mt++) {
        const int row = 32 * mt + c;
        const bool rok = row < NS;
        const float* __restrict__ Arow = Ab + row * NS;
        #pragma unroll
        for (int kt = 0; kt < 4; kt++) {
            FragU uh, ul;
            #pragma unroll
            for (int t = 0; t < 4; t++) {
                const int k0 = 16 * kt + 8 * h + 2 * t;
                const float e = (rok && k0     < NS) ? Arow[k0]     : 0.f;
                const float o = (rok && k0 + 1 < NS) ? Arow[k0 + 1] : 0.f;
                const unsigned ue = __float_as_uint(e), uo = __float_as_uint(o);
                uh.u[t] = (ue >> 16) | (uo & 0xFFFF0000u);
                const float re = e - __uint_as_float(ue & 0xFFFF0000u);
                const float ro = o - __uint_as_float(uo & 0xFFFF0000u);
                ul.u[t] = (__float_as_uint(re) >> 16) | (__float_as_uint(ro) & 0xFFFF0000u);
            }
            Ah[mt][kt] = uh.f; Al[mt][kt] = ul.f;
        }
    }

    // ---- prologue: stage state_0 = ctx[0] panel into S[0] (coop, coalesced)
    {
        const float* __restrict__ src = ctx + colbase;
        #pragma unroll
        for (int it = 0; it < 13; ++it) {
            const int idx = it * 384 + tid;          // float4 index in panel
            if (idx < (NS * HALFC) / 4) {
                const int row = idx / 96, cq = idx - row * 96;
                const float4 v = *reinterpret_cast<const float4*>(&src[row * ND + cq * 4]);
                *reinterpret_cast<float4*>(&S[0][row * SROW + cq * 4]) = v;
            }
        }
    }
    asm volatile("s_waitcnt lgkmcnt(0)" ::: "memory");
    __builtin_amdgcn_s_barrier();
    asm volatile("" ::: "memory");

    // ---- steps 1..45 ----
    for (int i = 1; i < NB; ++i) {
        float*       __restrict__ Scur  = S[i & 1];
        const float* __restrict__ Sprev = S[(i & 1) ^ 1];
        const float* __restrict__ ctxi  = ctx + (size_t)i * NS * ND;

        // (1) acc := ctx[i] — loads issued FIRST (ahead of this iter's stores)
        f32x16 acc[2][2];
        #pragma unroll
        for (int mt = 0; mt < 2; mt++)
            #pragma unroll
            for (int nt = 0; nt < 2; nt++)
                #pragma unroll
                for (int g = 0; g < 16; g++) {
                    const int rg = 32 * mt + (g & 3) + 8 * (g >> 2) + 4 * h;
                    acc[mt][nt][g] = (rg < NS)
                        ? ctxi[(size_t)rg * ND + colbase + w * 64 + 32 * nt + c] : 0.f;
                }

        // (2) cooperative contiguous store: Sprev -> rec[i-1]
        {
            float* __restrict__ dst = rec + ((size_t)(i - 1) * NB + b) * NS * ND + colbase;
            #pragma unroll
            for (int it = 0; it < 13; ++it) {
                const int idx = it * 384 + tid;
                if (idx < (NS * HALFC) / 4) {
                    const int row = idx / 96, cq = idx - row * 96;
                    const float4 v = *reinterpret_cast<const float4*>(&Sprev[row * SROW + cq * 4]);
                    *reinterpret_cast<float4*>(&dst[row * ND + cq * 4]) = v;
                }
            }
        }

        // (3) B-frags from Sprev (pack hi/lo bf16, identical values to R9) + MFMA
        #pragma unroll
        for (int nt = 0; nt < 2; nt++) {
            const int scn = w * 64 + 32 * nt + c;
            bfrag Bh[4], Bl[4];
            #pragma unroll
            for (int kt = 0; kt < 4; kt++) {
                float f[8];
                #pragma unroll
                for (int j = 0; j < 8; j++) {
                    const int rk = 16 * kt + 8 * h + j;
                    f[j] = (rk < NS) ? Sprev[rk * SROW + scn] : 0.f;
                }
                FragU uh, ul;
                #pragma unroll
                for (int t = 0; t < 4; t++) {
                    const unsigned b0 = __float_as_uint(f[2 * t]);
                    const unsigned b1 = __float_as_uint(f[2 * t + 1]);
                    uh.u[t] = (b0 >> 16) | (b1 & 0xFFFF0000u);
                    const float r0 = f[2 * t]     - __uint_as_float(b0 & 0xFFFF0000u);
                    const float r1 = f[2 * t + 1] - __uint_as_float(b1 & 0xFFFF0000u);
                    ul.u[t] = (__float_as_uint(r0) >> 16) | (__float_as_uint(r1) & 0xFFFF0000u);
                }
                Bh[kt] = uh.f; Bl[kt] = ul.f;
            }
            #pragma unroll
            for (int mt = 0; mt < 2; mt++) {
                f32x16 a = acc[mt][nt];
                #pragma unroll
                for (int kt = 0; kt < 4; kt++)
                    a = __builtin_amdgcn_mfma_f32_32x32x16_bf16(Ah[mt][kt], Bh[kt], a, 0, 0, 0);
                #pragma unroll
                for (int kt = 0; kt < 4; kt++)
                    a = __builtin_amdgcn_mfma_f32_32x32x16_bf16(Ah[mt][kt], Bl[kt], a, 0, 0, 0);
                #pragma unroll
                for (int kt = 0; kt < 4; kt++)
                    a = __builtin_amdgcn_mfma_f32_32x32x16_bf16(Al[mt][kt], Bh[kt], a, 0, 0, 0);
                acc[mt][nt] = a;
            }
        }

        // (4) stage acc -> Scur (safe: Scur's last readers were pre-barrier i-1)
        #pragma unroll
        for (int mt = 0; mt < 2; mt++)
            #pragma unroll
            for (int nt = 0; nt < 2; nt++)
                #pragma unroll
                for (int g = 0; g < 16; g++) {
                    const int rg = 32 * mt + (g & 3) + 8 * (g >> 2) + 4 * h;
                    if (rg < NS)
                        Scur[rg * SROW + w * 64 + 32 * nt + c] = acc[mt][nt][g];
                }

        // (5) LDS-only barrier (no vmcnt drain — stores keep floating)
        asm volatile("s_waitcnt lgkmcnt(0)" ::: "memory");
        __builtin_amdgcn_s_barrier();
        asm volatile("" ::: "memory");
    }

    // ---- epilogue: store final state panel rec[45] ----
    {
        const float* __restrict__ Sfin = S[(NB - 1) & 1];
        float* __restrict__ dst = rec + ((size_t)(NB - 1) * NB + b) * NS * ND + colbase;
        #pragma unroll
        for (int it = 0; it < 13; ++it) {
            const int idx = it * 384 + tid;
            if (idx < (NS * HALFC) / 4) {
                const int row = idx / 96, cq = idx - row * 96;
                const float4 v = *reinterpret_cast<const float4*>(&Sfin[row * SROW + cq * 4]);
                *reinterpret_cast<float4*>(&dst[row * ND + cq * 4]) = v;
            }
        }
    }
}

extern "C" void kernel_launch(void* const* d_in, const int* in_sizes, int n_in,
                              void* d_out, int out_size, void* d_ws, size_t ws_size,
                              hipStream_t stream) {
    const float* text_emb = (const float*)d_in[0];
    const float* emb      = (const float*)d_in[1];
    const float* Wq = (const float*)d_in[2]; const float* bq = (const float*)d_in[3];
    const float* Wk = (const float*)d_in[4]; const float* bk = (const float*)d_in[5];
    const float* Wv = (const float*)d_in[6]; const float* bv = (const float*)d_in[7];
    const float* lw = (const float*)d_in[8]; const float* lb = (const float*)d_in[9];

    float* out = (float*)d_out;
    float* ctx = out;                          // [46,50,768]
    float* rec = out + NB * NS * ND;           // [46,46,50,768]

    float* ws = (float*)d_ws;                  // needs 21.7 MB
    float* Q  = ws;
    float* K  = Q + NB * NS * ND;
    float* V  = K + NB * NS * ND;
    float* Ag = V + NB * NS * ND;              // gamma * Q_trans, [46,50,50]

    qkv_gemm<<<dim3(36, 12, 3), 256, 0, stream>>>(text_emb, emb, Wq, bq, Wk, bk, Wv, bv, Q, K, V);
    attn<<<dim3(NM), 64, 0, stream>>>(Q, K, V, lw, lb, Ag, ctx);
    recur<<<dim3(92), 384, 0, stream>>>(Ag, ctx, rec);
}

// Round 12
// 406.716 us; speedup vs baseline: 1.2792x; 1.2792x over previous
//
#include <hip/hip_runtime.h>
#include <math.h>

#define NB 46
#define NS 50
#define ND 768
#define GAMA 0.96875f
#define NM 2300   // NB*NS rows

using bfrag  = __attribute__((ext_vector_type(8))) short;   // 8 bf16 = 4 VGPRs
using f32x16 = __attribute__((ext_vector_type(16))) float;  // 32x32 acc

union FragU { unsigned u[4]; bfrag f; };

// ---------------- Kernel 1: QKV projections (+bias, +pe for Q,K) ----------
__global__ __launch_bounds__(256) void qkv_gemm(
    const float* __restrict__ text_emb, const float* __restrict__ emb,
    const float* __restrict__ Wq, const float* __restrict__ bq,
    const float* __restrict__ Wk, const float* __restrict__ bk,
    const float* __restrict__ Wv, const float* __restrict__ bv,
    float* __restrict__ Q, float* __restrict__ K, float* __restrict__ V)
{
    const int z = blockIdx.z;
    const float* X    = (z == 0) ? text_emb : emb;
    const float* W    = (z == 0) ? Wq : (z == 1) ? Wk : Wv;
    const float* bias = (z == 0) ? bq : (z == 1) ? bk : bv;
    float* out        = (z == 0) ? Q  : (z == 1) ? K  : V;

    __shared__ float Xs[16][68];
    __shared__ float Ws[16][68];

    const int tid = threadIdx.x;
    const int tx = tid & 15, ty = tid >> 4;
    const int m0 = blockIdx.x * 64, n0 = blockIdx.y * 64;

    const int lrow = tid >> 2;        // 0..63
    const int lk   = (tid & 3) * 4;   // 0,4,8,12

    float acc[4][4];
    #pragma unroll
    for (int i = 0; i < 4; i++)
        #pragma unroll
        for (int j = 0; j < 4; j++) acc[i][j] = 0.f;

    for (int k0 = 0; k0 < ND; k0 += 16) {
        float4 xv = make_float4(0.f, 0.f, 0.f, 0.f);
        const int xm = m0 + lrow;
        if (xm < NM) xv = *reinterpret_cast<const float4*>(&X[xm * ND + k0 + lk]);
        const float4 wv = *reinterpret_cast<const float4*>(&W[(n0 + lrow) * ND + k0 + lk]);
        Xs[lk + 0][lrow] = xv.x; Xs[lk + 1][lrow] = xv.y;
        Xs[lk + 2][lrow] = xv.z; Xs[lk + 3][lrow] = xv.w;
        Ws[lk + 0][lrow] = wv.x; Ws[lk + 1][lrow] = wv.y;
        Ws[lk + 2][lrow] = wv.z; Ws[lk + 3][lrow] = wv.w;
        __syncthreads();
        #pragma unroll
        for (int k = 0; k < 16; k++) {
            const float4 a  = *reinterpret_cast<const float4*>(&Xs[k][4 * ty]);
            const float4 b4 = *reinterpret_cast<const float4*>(&Ws[k][4 * tx]);
            const float av[4]  = {a.x,  a.y,  a.z,  a.w};
            const float bv4[4] = {b4.x, b4.y, b4.z, b4.w};
            #pragma unroll
            for (int i = 0; i < 4; i++)
                #pragma unroll
                for (int j = 0; j < 4; j++) acc[i][j] += av[i] * bv4[j];
        }
        __syncthreads();
    }

    const float C2 = -0.0239861701969175f; // -2*ln(10000)/768
    #pragma unroll
    for (int i = 0; i < 4; i++) {
        const int m = m0 + 4 * ty + i;
        if (m >= NM) continue;
        const int bpos = m / NS;  // pe indexed by BATCH position (faithful to source)
        #pragma unroll
        for (int j = 0; j < 4; j++) {
            const int n = n0 + 4 * tx + j;
            float v = acc[i][j] + bias[n];
            if (z < 2) {
                const int h = n >> 1;
                const float ang = (float)bpos * expf((float)h * C2);
                v += (n & 1) ? cosf(ang) : sinf(ang);
            }
            out[m * ND + n] = v;
        }
    }
}

// ---------------- Kernel 2: scores+softmax+ctx, and Ag = gamma*Q_trans -----
__global__ __launch_bounds__(64) void attn(
    const float* __restrict__ Q, const float* __restrict__ K,
    const float* __restrict__ V,
    const float* __restrict__ lin_w, const float* __restrict__ lin_b,
    float* __restrict__ Ag, float* __restrict__ ctx_out)
{
    const int bq = blockIdx.x;
    const int b = bq / NS, q = bq % NS;
    const int lane = threadIdx.x;

    const float* Qr = Q + (b * NS + q) * ND;
    float qv[12];
    #pragma unroll
    for (int m = 0; m < 12; m++) qv[m] = Qr[m * 64 + lane];

    // scores: lane k ends up holding score[k]*8
    float mysc = 0.f;
    for (int k = 0; k < NS; k++) {
        const float* Kr = K + (b * NS + k) * ND;
        float s = 0.f;
        #pragma unroll
        for (int m = 0; m < 12; m++) s += qv[m] * Kr[m * 64 + lane];
        #pragma unroll
        for (int off = 32; off; off >>= 1) s += __shfl_xor(s, off);
        if (lane == k) mysc = s * 8.f;
    }
    // Q_trans row q: lane j holds Qt[j]; write Ag = gamma*(Qt + lin_b)
    float myqt = 0.f;
    for (int j = 0; j < NS; j++) {
        const float* Lr = lin_w + j * ND;
        float s = 0.f;
        #pragma unroll
        for (int m = 0; m < 12; m++) s += qv[m] * Lr[m * 64 + lane];
        #pragma unroll
        for (int off = 32; off; off >>= 1) s += __shfl_xor(s, off);
        if (lane == j) myqt = s;
    }
    if (lane < NS)
        Ag[b * (NS * NS) + q * NS + lane] = GAMA * (myqt + lin_b[lane]);

    // softmax over lanes 0..49
    const float sc = (lane < NS) ? mysc : -INFINITY;
    float mx = sc;
    #pragma unroll
    for (int off = 32; off; off >>= 1) mx = fmaxf(mx, __shfl_xor(mx, off));
    const float e = (lane < NS) ? expf(sc - mx) : 0.f;
    float sum = e;
    #pragma unroll
    for (int off = 32; off; off >>= 1) sum += __shfl_xor(sum, off);
    const float p = e / sum;

    // ctx row = sum_k p_k * V[b,k,:]
    float acc[12];
    #pragma unroll
    for (int m = 0; m < 12; m++) acc[m] = 0.f;
    for (int k = 0; k < NS; k++) {
        const float pk = __shfl(p, k);
        const float* Vr = V + (b * NS + k) * ND;
        #pragma unroll
        for (int m = 0; m < 12; m++) acc[m] += pk * Vr[m * 64 + lane];
    }
    float* Cr = ctx_out + (b * NS + q) * ND;
    #pragma unroll
    for (int m = 0; m < 12; m++) Cr[m * 64 + lane] = acc[m];
}

// ---------------- Kernel 3: gamma-decay recurrence via MFMA ----------------
// rec[i,b,:,:] = Ag_b @ rec[i-1,b,:,:] + ctx[i], padded 50->64 on M,K.
// R10 geometry (best): one wave per (b, 32-col chunk), 1104 blocks; A in
// bf16 hi/lo frags loaded once; state packed in LDS P[64][32]; no barriers.
// R11 lesson: a perfectly contiguous write pattern ran SLOWER (1.0 TB/s) ->
// the ~1.4 TB/s was never a DRAM-pattern ceiling. The stall is the vmcnt
// FIFO: at VGPR=160 occupancy is 1 wave/SIMD (no TLP), and the per-step
// wait for ctx loads issued 1 step ago sits behind stores_{i-1} -> every
// step pays the previous step's store retirement. R12: prefetch distance 2
// (three ctx buffers, loop unrolled x3, static indices): the wait for ctx_i
// (issued step i-2) only forces retirement of stores_{i-2} -> stores get
// ~2 steps to drain in the shadow of compute.
__device__ __forceinline__ void rec_step(
    int i, int b, int d0, int c, int h,
    const bfrag (&Ah)[2][4], const bfrag (&Al)[2][4],
    float (&cur)[2][16], float (&ld2)[2][16],   // ld2 receives ctx_{i+2}
    unsigned* P, const float* __restrict__ ctx, float* __restrict__ rec)
{
    // acc := ctx_i (pad rows already 0 in cur); cur is dead after this copy
    f32x16 acc[2];
    #pragma unroll
    for (int mt = 0; mt < 2; mt++)
        #pragma unroll
        for (int g = 0; g < 16; g++)
            acc[mt][g] = cur[mt][g];

    // prefetch ctx_{i+2} BEFORE this step's stores (2-step FIFO slack)
    if (i + 2 < NB) {
        const float* __restrict__ ctxn = ctx + (size_t)(i + 2) * NS * ND + d0 + c;
        #pragma unroll
        for (int mt = 0; mt < 2; mt++)
            #pragma unroll
            for (int g = 0; g < 16; g++) {
                const int rg = 32 * mt + (g & 3) + 8 * (g >> 2) + 4 * h;
                ld2[mt][g] = (rg < NS) ? ctxn[(size_t)rg * ND] : 0.f;
            }
    }

    // B-frags of s_{i-1} from P
    bfrag Bh[4], Bl[4];
    #pragma unroll
    for (int kt = 0; kt < 4; kt++) {
        unsigned pw[8];
        #pragma unroll
        for (int j = 0; j < 8; j++)
            pw[j] = P[(16 * kt + 8 * h + j) * 32 + c];
        FragU uh, ul;
        #pragma unroll
        for (int t = 0; t < 4; t++) {
            uh.u[t] = (pw[2 * t] >> 16)     | (pw[2 * t + 1] & 0xFFFF0000u);
            ul.u[t] = (pw[2 * t] & 0xFFFFu) | (pw[2 * t + 1] << 16);
        }
        Bh[kt] = uh.f; Bl[kt] = ul.f;
    }

    // 12 MFMA per mt: hi*hi, hi*lo, lo*hi
    #pragma unroll
    for (int mt = 0; mt < 2; mt++) {
        f32x16 a = acc[mt];
        #pragma unroll
        for (int kt = 0; kt < 4; kt++)
            a = __builtin_amdgcn_mfma_f32_32x32x16_bf16(Ah[mt][kt], Bh[kt], a, 0, 0, 0);
        #pragma unroll
        for (int kt = 0; kt < 4; kt++)
            a = __builtin_amdgcn_mfma_f32_32x32x16_bf16(Ah[mt][kt], Bl[kt], a, 0, 0, 0);
        #pragma unroll
        for (int kt = 0; kt < 4; kt++)
            a = __builtin_amdgcn_mfma_f32_32x32x16_bf16(Al[mt][kt], Bh[kt], a, 0, 0, 0);
        acc[mt] = a;
    }

    // repack state into P (pad rows produce exact 0) + store rec
    float* __restrict__ reci = rec + (size_t)(i * NB + b) * NS * ND + d0 + c;
    #pragma unroll
    for (int mt = 0; mt < 2; mt++)
        #pragma unroll
        for (int g = 0; g < 16; g++) {
            const int rg = 32 * mt + (g & 3) + 8 * (g >> 2) + 4 * h;
            const float v = acc[mt][g];
            const unsigned hi = __float_as_uint(v) & 0xFFFF0000u;
            const float res = v - __uint_as_float(hi);
            P[rg * 32 + c] = hi | (__float_as_uint(res) >> 16);
            if (rg < NS)
                reci[(size_t)rg * ND] = v;
        }
}

__global__ __launch_bounds__(64, 1) void recur(
    const float* __restrict__ Ag, const float* __restrict__ ctx,
    float* __restrict__ rec)
{
    const int blk   = blockIdx.x;          // 0..1103
    const int b     = blk / 24;
    const int chunk = blk - b * 24;        // 0..23 -> 32 cols
    const int l     = threadIdx.x;
    const int c     = l & 31;
    const int h     = l >> 5;
    const int d0    = chunk * 32;

    __shared__ unsigned P[64 * 32];        // packed state (hi16|lo16), 8 KB

    // ---- A fragments (hi/lo), ONCE, straight from global (L2-resident) ----
    const float* __restrict__ Ab = Ag + b * (NS * NS);
    bfrag Ah[2][4], Al[2][4];
    #pragma unroll
    for (int mt = 0; mt < 2; mt++) {
        const int row = 32 * mt + c;
        const bool rok = row < NS;
        const float* __restrict__ Arow = Ab + row * NS;
        #pragma unroll
        for (int kt = 0; kt < 4; kt++) {
            FragU uh, ul;
            #pragma unroll
            for (int t = 0; t < 4; t++) {
                const int k0 = 16 * kt + 8 * h + 2 * t;
                const float e = (rok && k0     < NS) ? Arow[k0]     : 0.f;
                const float o = (rok && k0 + 1 < NS) ? Arow[k0 + 1] : 0.f;
                const unsigned ue = __float_as_uint(e), uo = __float_as_uint(o);
                uh.u[t] = (ue >> 16) | (uo & 0xFFFF0000u);
                const float re = e - __uint_as_float(ue & 0xFFFF0000u);
                const float ro = o - __uint_as_float(uo & 0xFFFF0000u);
                ul.u[t] = (__float_as_uint(re) >> 16) | (__float_as_uint(ro) & 0xFFFF0000u);
            }
            Ah[mt][kt] = uh.f; Al[mt][kt] = ul.f;
        }
    }

    // ---- prologue: cv0 = ctx[0]; cvA = ctx[1]; cvB = ctx[2]; THEN stores ----
    float cvA[2][16], cvB[2][16], cvC[2][16];
    {
        float cv0[2][16];
        const float* __restrict__ c0 = ctx + d0 + c;
        #pragma unroll
        for (int mt = 0; mt < 2; mt++)
            #pragma unroll
            for (int g = 0; g < 16; g++) {
                const int rg = 32 * mt + (g & 3) + 8 * (g >> 2) + 4 * h;
                cv0[mt][g] = (rg < NS) ? c0[(size_t)rg * ND] : 0.f;
            }
        const float* __restrict__ c1 = ctx + (size_t)NS * ND + d0 + c;
        #pragma unroll
        for (int mt = 0; mt < 2; mt++)
            #pragma unroll
            for (int g = 0; g < 16; g++) {
                const int rg = 32 * mt + (g & 3) + 8 * (g >> 2) + 4 * h;
                cvA[mt][g] = (rg < NS) ? c1[(size_t)rg * ND] : 0.f;
            }
        const float* __restrict__ c2 = ctx + (size_t)2 * NS * ND + d0 + c;
        #pragma unroll
        for (int mt = 0; mt < 2; mt++)
            #pragma unroll
            for (int g = 0; g < 16; g++) {
                const int rg = 32 * mt + (g & 3) + 8 * (g >> 2) + 4 * h;
                cvB[mt][g] = (rg < NS) ? c2[(size_t)rg * ND] : 0.f;
            }
        // step 0: pack state_0 into P, store rec[0]
        float* __restrict__ r0 = rec + (size_t)b * NS * ND + d0 + c;
        #pragma unroll
        for (int mt = 0; mt < 2; mt++)
            #pragma unroll
            for (int g = 0; g < 16; g++) {
                const int rg = 32 * mt + (g & 3) + 8 * (g >> 2) + 4 * h;
                const float v = cv0[mt][g];
                const unsigned hi = __float_as_uint(v) & 0xFFFF0000u;
                const float res = v - __uint_as_float(hi);
                P[rg * 32 + c] = hi | (__float_as_uint(res) >> 16);
                if (rg < NS)
                    r0[(size_t)rg * ND] = v;
            }
    }

    // ---- steps 1..45, 3x unrolled rotation (45 = 3*15, static indices) ----
    for (int i = 1; i < NB; i += 3) {
        rec_step(i,     b, d0, c, h, Ah, Al, cvA, cvC, P, ctx, rec);
        rec_step(i + 1, b, d0, c, h, Ah, Al, cvB, cvA, P, ctx, rec);
        rec_step(i + 2, b, d0, c, h, Ah, Al, cvC, cvB, P, ctx, rec);
    }
}

extern "C" void kernel_launch(void* const* d_in, const int* in_sizes, int n_in,
                              void* d_out, int out_size, void* d_ws, size_t ws_size,
                              hipStream_t stream) {
    const float* text_emb = (const float*)d_in[0];
    const float* emb      = (const float*)d_in[1];
    const float* Wq = (const float*)d_in[2]; const float* bq = (const float*)d_in[3];
    const float* Wk = (const float*)d_in[4]; const float* bk = (const float*)d_in[5];
    const float* Wv = (const float*)d_in[6]; const float* bv = (const float*)d_in[7];
    const float* lw = (const float*)d_in[8]; const float* lb = (const float*)d_in[9];

    float* out = (float*)d_out;
    float* ctx = out;                          // [46,50,768]
    float* rec = out + NB * NS * ND;           // [46,46,50,768]

    float* ws = (float*)d_ws;                  // needs 21.7 MB
    float* Q  = ws;
    float* K  = Q + NB * NS * ND;
    float* V  = K + NB * NS * ND;
    float* Ag = V + NB * NS * ND;              // gamma * Q_trans, [46,50,50]

    qkv_gemm<<<dim3(36, 12, 3), 256, 0, stream>>>(text_emb, emb, Wq, bq, Wk, bk, Wv, bv, Q, K, V);
    attn<<<dim3(NM), 64, 0, stream>>>(Q, K, V, lw, lb, Ag, ctx);
    recur<<<dim3(1104), 64, 0, stream>>>(Ag, ctx, rec);
}

// Round 13
// 287.048 us; speedup vs baseline: 1.8125x; 1.4169x over previous
//
#include <hip/hip_runtime.h>
#include <math.h>

#define NB 46
#define NS 50
#define ND 768
#define GAMA 0.96875f
#define NM 2300   // NB*NS rows

using bfrag  = __attribute__((ext_vector_type(8))) short;   // 8 bf16 = 4 VGPRs
using f32x16 = __attribute__((ext_vector_type(16))) float;  // 32x32 acc

union FragU { unsigned u[4]; bfrag f; };

// ---------------- Kernel 1: QKV projections (+bias, +pe for Q,K) ----------
__global__ __launch_bounds__(256) void qkv_gemm(
    const float* __restrict__ text_emb, const float* __restrict__ emb,
    const float* __restrict__ Wq, const float* __restrict__ bq,
    const float* __restrict__ Wk, const float* __restrict__ bk,
    const float* __restrict__ Wv, const float* __restrict__ bv,
    float* __restrict__ Q, float* __restrict__ K, float* __restrict__ V)
{
    const int z = blockIdx.z;
    const float* X    = (z == 0) ? text_emb : emb;
    const float* W    = (z == 0) ? Wq : (z == 1) ? Wk : Wv;
    const float* bias = (z == 0) ? bq : (z == 1) ? bk : bv;
    float* out        = (z == 0) ? Q  : (z == 1) ? K  : V;

    __shared__ float Xs[16][68];
    __shared__ float Ws[16][68];

    const int tid = threadIdx.x;
    const int tx = tid & 15, ty = tid >> 4;
    const int m0 = blockIdx.x * 64, n0 = blockIdx.y * 64;

    const int lrow = tid >> 2;        // 0..63
    const int lk   = (tid & 3) * 4;   // 0,4,8,12

    float acc[4][4];
    #pragma unroll
    for (int i = 0; i < 4; i++)
        #pragma unroll
        for (int j = 0; j < 4; j++) acc[i][j] = 0.f;

    for (int k0 = 0; k0 < ND; k0 += 16) {
        float4 xv = make_float4(0.f, 0.f, 0.f, 0.f);
        const int xm = m0 + lrow;
        if (xm < NM) xv = *reinterpret_cast<const float4*>(&X[xm * ND + k0 + lk]);
        const float4 wv = *reinterpret_cast<const float4*>(&W[(n0 + lrow) * ND + k0 + lk]);
        Xs[lk + 0][lrow] = xv.x; Xs[lk + 1][lrow] = xv.y;
        Xs[lk + 2][lrow] = xv.z; Xs[lk + 3][lrow] = xv.w;
        Ws[lk + 0][lrow] = wv.x; Ws[lk + 1][lrow] = wv.y;
        Ws[lk + 2][lrow] = wv.z; Ws[lk + 3][lrow] = wv.w;
        __syncthreads();
        #pragma unroll
        for (int k = 0; k < 16; k++) {
            const float4 a  = *reinterpret_cast<const float4*>(&Xs[k][4 * ty]);
            const float4 b4 = *reinterpret_cast<const float4*>(&Ws[k][4 * tx]);
            const float av[4]  = {a.x,  a.y,  a.z,  a.w};
            const float bv4[4] = {b4.x, b4.y, b4.z, b4.w};
            #pragma unroll
            for (int i = 0; i < 4; i++)
                #pragma unroll
                for (int j = 0; j < 4; j++) acc[i][j] += av[i] * bv4[j];
        }
        __syncthreads();
    }

    const float C2 = -0.0239861701969175f; // -2*ln(10000)/768
    #pragma unroll
    for (int i = 0; i < 4; i++) {
        const int m = m0 + 4 * ty + i;
        if (m >= NM) continue;
        const int bpos = m / NS;  // pe indexed by BATCH position (faithful to source)
        #pragma unroll
        for (int j = 0; j < 4; j++) {
            const int n = n0 + 4 * tx + j;
            float v = acc[i][j] + bias[n];
            if (z < 2) {
                const int h = n >> 1;
                const float ang = (float)bpos * expf((float)h * C2);
                v += (n & 1) ? cosf(ang) : sinf(ang);
            }
            out[m * ND + n] = v;
        }
    }
}

// ---------------- Kernel 2: scores+softmax+ctx, and Ag = gamma*Q_trans -----
__global__ __launch_bounds__(64) void attn(
    const float* __restrict__ Q, const float* __restrict__ K,
    const float* __restrict__ V,
    const float* __restrict__ lin_w, const float* __restrict__ lin_b,
    float* __restrict__ Ag, float* __restrict__ ctx_out)
{
    const int bq = blockIdx.x;
    const int b = bq / NS, q = bq % NS;
    const int lane = threadIdx.x;

    const float* Qr = Q + (b * NS + q) * ND;
    float qv[12];
    #pragma unroll
    for (int m = 0; m < 12; m++) qv[m] = Qr[m * 64 + lane];

    // scores: lane k ends up holding score[k]*8
    float mysc = 0.f;
    for (int k = 0; k < NS; k++) {
        const float* Kr = K + (b * NS + k) * ND;
        float s = 0.f;
        #pragma unroll
        for (int m = 0; m < 12; m++) s += qv[m] * Kr[m * 64 + lane];
        #pragma unroll
        for (int off = 32; off; off >>= 1) s += __shfl_xor(s, off);
        if (lane == k) mysc = s * 8.f;
    }
    // Q_trans row q: lane j holds Qt[j]; write Ag = gamma*(Qt + lin_b)
    float myqt = 0.f;
    for (int j = 0; j < NS; j++) {
        const float* Lr = lin_w + j * ND;
        float s = 0.f;
        #pragma unroll
        for (int m = 0; m < 12; m++) s += qv[m] * Lr[m * 64 + lane];
        #pragma unroll
        for (int off = 32; off; off >>= 1) s += __shfl_xor(s, off);
        if (lane == j) myqt = s;
    }
    if (lane < NS)
        Ag[b * (NS * NS) + q * NS + lane] = GAMA * (myqt + lin_b[lane]);

    // softmax over lanes 0..49
    const float sc = (lane < NS) ? mysc : -INFINITY;
    float mx = sc;
    #pragma unroll
    for (int off = 32; off; off >>= 1) mx = fmaxf(mx, __shfl_xor(mx, off));
    const float e = (lane < NS) ? expf(sc - mx) : 0.f;
    float sum = e;
    #pragma unroll
    for (int off = 32; off; off >>= 1) sum += __shfl_xor(sum, off);
    const float p = e / sum;

    // ctx row = sum_k p_k * V[b,k,:]
    float acc[12];
    #pragma unroll
    for (int m = 0; m < 12; m++) acc[m] = 0.f;
    for (int k = 0; k < NS; k++) {
        const float pk = __shfl(p, k);
        const float* Vr = V + (b * NS + k) * ND;
        #pragma unroll
        for (int m = 0; m < 12; m++) acc[m] += pk * Vr[m * 64 + lane];
    }
    float* Cr = ctx_out + (b * NS + q) * ND;
    #pragma unroll
    for (int m = 0; m < 12; m++) Cr[m * 64 + lane] = acc[m];
}

// ---------------- Kernel 3: gamma-decay recurrence via MFMA ----------------
// rec[i,b,:,:] = Ag_b @ rec[i-1,b,:,:] + ctx[i], padded 50->64 on M,K.
// R10 geometry: one wave per (b, 32-col chunk), 1104 blocks; A in bf16 hi/lo
// frags loaded once; no barriers (single-wave lockstep: all LDS hazards are
// resolved by program order).
// R12 lesson: 57 VMEM dword ops/step issue near-SERIALLY (~200 cyc/op): at
// ~200 VGPR there's no headroom to keep 57 addr+dest registers in flight, so
// the compiler issues->waits->reuses; and vmcnt's 6-bit cap (63) makes >1
// step of slack unencodable (why dist-2 == dist-1). R13: 4x fewer / 4x
// fatter VMEM via LDS layout-transpose:
//   loads:  7x dwordx4 (8rows x 4cols/lane) -> ds_write_b128 -> Cx[64][32]
//           -> acc init reads C-layout b32 (bitwise-identical f32 roundtrip)
//   stores: acc -> Sf[64][32] f32 (replaces packed P; B-frags pack hi/lo
//           from Sf on the fly, same values as the P path) -> ds_read_b128
//           -> 7x dwordx4 stores.
// 14 VMEM ops/step (was 57): 63-cap = 4.5 steps of slack, ~42 VGPRs covers
// 7 in-flight fat ops.
__global__ __launch_bounds__(64, 1) void recur(
    const float* __restrict__ Ag, const float* __restrict__ ctx,
    float* __restrict__ rec)
{
    const int blk   = blockIdx.x;          // 0..1103
    const int b     = blk / 24;
    const int chunk = blk - b * 24;        // 0..23 -> 32 cols
    const int l     = threadIdx.x;
    const int c     = l & 31;
    const int h     = l >> 5;
    const int d0    = chunk * 32;
    const int srow  = l >> 3;              // 0..7   (fat-op tile row)
    const int scol  = (l & 7) * 4;         // 0,4..28 (fat-op tile col)

    __shared__ float Sf[64 * 32];          // state f32, 8 KB
    __shared__ float Cx[64 * 32];          // ctx staging, 8 KB

    // ---- A fragments (hi/lo), ONCE, straight from global (L2-resident) ----
    const float* __restrict__ Ab = Ag + b * (NS * NS);
    bfrag Ah[2][4], Al[2][4];
    #pragma unroll
    for (int mt = 0; mt < 2; mt++) {
        const int row = 32 * mt + c;
        const bool rok = row < NS;
        const float* __restrict__ Arow = Ab + row * NS;
        #pragma unroll
        for (int kt = 0; kt < 4; kt++) {
            FragU uh, ul;
            #pragma unroll
            for (int t = 0; t < 4; t++) {
                const int k0 = 16 * kt + 8 * h + 2 * t;
                const float e = (rok && k0     < NS) ? Arow[k0]     : 0.f;
                const float o = (rok && k0 + 1 < NS) ? Arow[k0 + 1] : 0.f;
                const unsigned ue = __float_as_uint(e), uo = __float_as_uint(o);
                uh.u[t] = (ue >> 16) | (uo & 0xFFFF0000u);
                const float re = e - __uint_as_float(ue & 0xFFFF0000u);
                const float ro = o - __uint_as_float(uo & 0xFFFF0000u);
                ul.u[t] = (__float_as_uint(re) >> 16) | (__float_as_uint(ro) & 0xFFFF0000u);
            }
            Ah[mt][kt] = uh.f; Al[mt][kt] = ul.f;
        }
    }

    // ---- zero pad rows 48..63 of both LDS arrays (48,49 overwritten below)
    {
        const float4 z = make_float4(0.f, 0.f, 0.f, 0.f);
        *reinterpret_cast<float4*>(&Cx[(48 + srow) * 32 + scol]) = z;
        *reinterpret_cast<float4*>(&Cx[(56 + srow) * 32 + scol]) = z;
        *reinterpret_cast<float4*>(&Sf[(48 + srow) * 32 + scol]) = z;
        *reinterpret_cast<float4*>(&Sf[(56 + srow) * 32 + scol]) = z;
    }

    // ---- step 0: load ctx_0 (fat), store rec_0 (fat), seed Sf ----
    float4 creg[7];
    #pragma unroll
    for (int it = 0; it < 7; ++it) creg[it] = make_float4(0.f, 0.f, 0.f, 0.f);
    {
        const float* __restrict__ src = ctx + d0;
        #pragma unroll
        for (int it = 0; it < 7; ++it) {
            const int r = it * 8 + srow;
            if (r < NS)
                creg[it] = *reinterpret_cast<const float4*>(&src[(size_t)r * ND + scol]);
        }
        float* __restrict__ r0 = rec + (size_t)b * NS * ND + d0;
        #pragma unroll
        for (int it = 0; it < 7; ++it) {
            const int r = it * 8 + srow;
            if (r < NS) {
                *reinterpret_cast<float4*>(&Sf[r * 32 + scol]) = creg[it];
                *reinterpret_cast<float4*>(&r0[(size_t)r * ND + scol]) = creg[it];
            }
        }
    }
    // ---- load ctx_1 -> cregs (consumed at step 1) ----
    {
        const float* __restrict__ src = ctx + (size_t)NS * ND + d0;
        #pragma unroll
        for (int it = 0; it < 7; ++it) {
            const int r = it * 8 + srow;
            if (r < NS)
                creg[it] = *reinterpret_cast<const float4*>(&src[(size_t)r * ND + scol]);
        }
    }

    // ---- steps 1..45 ----
    for (int i = 1; i < NB; ++i) {
        // [A] flush cregs (ctx_i) -> Cx (waits only on own loads, vmcnt(7))
        #pragma unroll
        for (int it = 0; it < 7; ++it) {
            const int r = it * 8 + srow;
            if (r < NS)
                *reinterpret_cast<float4*>(&Cx[r * 32 + scol]) = creg[it];
        }
        // [B] issue fat loads of ctx_{i+1}
        if (i + 1 < NB) {
            const float* __restrict__ src = ctx + (size_t)(i + 1) * NS * ND + d0;
            #pragma unroll
            for (int it = 0; it < 7; ++it) {
                const int r = it * 8 + srow;
                if (r < NS)
                    creg[it] = *reinterpret_cast<const float4*>(&src[(size_t)r * ND + scol]);
            }
        }
        // [C] acc init from Cx (C-layout; pad rows read exact 0)
        f32x16 acc[2];
        #pragma unroll
        for (int mt = 0; mt < 2; mt++)
            #pragma unroll
            for (int g = 0; g < 16; g++) {
                const int rg = 32 * mt + (g & 3) + 8 * (g >> 2) + 4 * h;
                acc[mt][g] = Cx[rg * 32 + c];
            }
        // [D] B-frags of s_{i-1} from Sf (pack hi/lo; identical values to P path)
        bfrag Bh[4], Bl[4];
        #pragma unroll
        for (int kt = 0; kt < 4; kt++) {
            float f[8];
            #pragma unroll
            for (int j = 0; j < 8; j++)
                f[j] = Sf[(16 * kt + 8 * h + j) * 32 + c];
            FragU uh, ul;
            #pragma unroll
            for (int t = 0; t < 4; t++) {
                const unsigned b0 = __float_as_uint(f[2 * t]);
                const unsigned b1 = __float_as_uint(f[2 * t + 1]);
                uh.u[t] = (b0 >> 16) | (b1 & 0xFFFF0000u);
                const float r0f = f[2 * t]     - __uint_as_float(b0 & 0xFFFF0000u);
                const float r1f = f[2 * t + 1] - __uint_as_float(b1 & 0xFFFF0000u);
                ul.u[t] = (__float_as_uint(r0f) >> 16) | (__float_as_uint(r1f) & 0xFFFF0000u);
            }
            Bh[kt] = uh.f; Bl[kt] = ul.f;
        }
        // [E] 12 MFMA per mt: hi*hi, hi*lo, lo*hi
        #pragma unroll
        for (int mt = 0; mt < 2; mt++) {
            f32x16 a = acc[mt];
            #pragma unroll
            for (int kt = 0; kt < 4; kt++)
                a = __builtin_amdgcn_mfma_f32_32x32x16_bf16(Ah[mt][kt], Bh[kt], a, 0, 0, 0);
            #pragma unroll
            for (int kt = 0; kt < 4; kt++)
                a = __builtin_amdgcn_mfma_f32_32x32x16_bf16(Ah[mt][kt], Bl[kt], a, 0, 0, 0);
            #pragma unroll
            for (int kt = 0; kt < 4; kt++)
                a = __builtin_amdgcn_mfma_f32_32x32x16_bf16(Al[mt][kt], Bh[kt], a, 0, 0, 0);
            acc[mt] = a;
        }
        // [F] acc -> Sf (all 64 rows; pad rows are exact 0; after [D] reads
        // in program order -> safe, single-wave lockstep)
        #pragma unroll
        for (int mt = 0; mt < 2; mt++)
            #pragma unroll
            for (int g = 0; g < 16; g++) {
                const int rg = 32 * mt + (g & 3) + 8 * (g >> 2) + 4 * h;
                Sf[rg * 32 + c] = acc[mt][g];
            }
        // [G]+[H] fat read-back + fat store of rec_i
        float* __restrict__ reci = rec + (size_t)(i * NB + b) * NS * ND + d0;
        #pragma unroll
        for (int it = 0; it < 7; ++it) {
            const int r = it * 8 + srow;
            if (r < NS) {
                const float4 v = *reinterpret_cast<const float4*>(&Sf[r * 32 + scol]);
                *reinterpret_cast<float4*>(&reci[(size_t)r * ND + scol]) = v;
            }
        }
    }
}

extern "C" void kernel_launch(void* const* d_in, const int* in_sizes, int n_in,
                              void* d_out, int out_size, void* d_ws, size_t ws_size,
                              hipStream_t stream) {
    const float* text_emb = (const float*)d_in[0];
    const float* emb      = (const float*)d_in[1];
    const float* Wq = (const float*)d_in[2]; const float* bq = (const float*)d_in[3];
    const float* Wk = (const float*)d_in[4]; const float* bk = (const float*)d_in[5];
    const float* Wv = (const float*)d_in[6]; const float* bv = (const float*)d_in[7];
    const float* lw = (const float*)d_in[8]; const float* lb = (const float*)d_in[9];

    float* out = (float*)d_out;
    float* ctx = out;                          // [46,50,768]
    float* rec = out + NB * NS * ND;           // [46,46,50,768]

    float* ws = (float*)d_ws;                  // needs 21.7 MB
    float* Q  = ws;
    float* K  = Q + NB * NS * ND;
    float* V  = K + NB * NS * ND;
    float* Ag = V + NB * NS * ND;              // gamma * Q_trans, [46,50,50]

    qkv_gemm<<<dim3(36, 12, 3), 256, 0, stream>>>(text_emb, emb, Wq, bq, Wk, bk, Wv, bv, Q, K, V);
    attn<<<dim3(NM), 64, 0, stream>>>(Q, K, V, lw, lb, Ag, ctx);
    recur<<<dim3(1104), 64, 0, stream>>>(Ag, ctx, rec);
}

// Round 14
// 285.602 us; speedup vs baseline: 1.8217x; 1.0051x over previous
//
#include <hip/hip_runtime.h>
#include <math.h>

#define NB 46
#define NS 50
#define ND 768
#define GAMA 0.96875f
#define NM 2300   // NB*NS rows

using bfrag  = __attribute__((ext_vector_type(8))) short;   // 8 bf16 = 4 VGPRs
using f32x16 = __attribute__((ext_vector_type(16))) float;  // 32x32 acc

union FragU { unsigned u[4]; bfrag f; };

// hi/lo bf16 split of 8 f32 (truncation; combined ~16-bit mantissa)
__device__ __forceinline__ void cvt_hilo(const float f[8], bfrag& fh, bfrag& fl)
{
    FragU uh, ul;
    #pragma unroll
    for (int t = 0; t < 4; t++) {
        const unsigned b0 = __float_as_uint(f[2 * t]);
        const unsigned b1 = __float_as_uint(f[2 * t + 1]);
        uh.u[t] = (b0 >> 16) | (b1 & 0xFFFF0000u);
        const float r0 = f[2 * t]     - __uint_as_float(b0 & 0xFFFF0000u);
        const float r1 = f[2 * t + 1] - __uint_as_float(b1 & 0xFFFF0000u);
        ul.u[t] = (__float_as_uint(r0) >> 16) | (__float_as_uint(r1) & 0xFFFF0000u);
    }
    fh = uh.f; fl = ul.f;
}

// ---------------- Kernel 1: QKV projections via MFMA (hi/lo bf16) ---------
// out[m,n] = sum_k X[m,k]*W[n,k] + bias[n] (+ pe for z<2).
// R13 analysis: fp32 vector GEMM was ~95us at ~55% of the 157TF vector
// ceiling; CDNA4 has no fp32 MFMA but the hi/lo bf16 split (validated in
// recur, 16-bit effective mantissa) gives XW ~= Xh@Wh + Xh@Wl + Xl@Wh on the
// 2.5PF matrix pipe. Logit error ~1.5e-3 -> ctx err ~1e-3, ~30x under the
// bf16-floored threshold. 4 waves = 2x2 quadrants of a 64x64 tile; per
// K-step-16 each lane loads 8 X + 8 W floats (dwordx4, L2-resident),
// converts hi/lo in-register, 3 MFMAs. Out-of-range m rows only pollute
// acc rows the guarded epilogue never stores (row-0 reads are finite).
__global__ __launch_bounds__(256) void qkv_gemm(
    const float* __restrict__ text_emb, const float* __restrict__ emb,
    const float* __restrict__ Wq, const float* __restrict__ bq,
    const float* __restrict__ Wk, const float* __restrict__ bk,
    const float* __restrict__ Wv, const float* __restrict__ bv,
    float* __restrict__ Q, float* __restrict__ K, float* __restrict__ V)
{
    const int z = blockIdx.z;
    const float* X    = (z == 0) ? text_emb : emb;
    const float* W    = (z == 0) ? Wq : (z == 1) ? Wk : Wv;
    const float* bias = (z == 0) ? bq : (z == 1) ? bk : bv;
    float* out        = (z == 0) ? Q  : (z == 1) ? K  : V;

    const int tid = threadIdx.x;
    const int w   = tid >> 6;           // wave 0..3
    const int l   = tid & 63;
    const int c   = l & 31;
    const int h   = l >> 5;
    const int wm  = w >> 1, wn = w & 1; // quadrant
    const int m0  = blockIdx.x * 64, n0 = blockIdx.y * 64;

    const int mrow = m0 + 32 * wm + c;               // A row (X row)
    const int nrow = n0 + 32 * wn + c;               // B col (W row)
    const bool mok = mrow < NM;
    const float* __restrict__ Xr = X + (size_t)(mok ? mrow : 0) * ND + 8 * h;
    const float* __restrict__ Wr = W + (size_t)nrow * ND + 8 * h;

    f32x16 acc;
    #pragma unroll
    for (int g = 0; g < 16; g++) acc[g] = 0.f;

    #pragma unroll 2
    for (int kk = 0; kk < ND; kk += 16) {
        float xa[8], wb[8];
        {
            const float4 x0 = *reinterpret_cast<const float4*>(Xr + kk);
            const float4 x1 = *reinterpret_cast<const float4*>(Xr + kk + 4);
            const float4 w0 = *reinterpret_cast<const float4*>(Wr + kk);
            const float4 w1 = *reinterpret_cast<const float4*>(Wr + kk + 4);
            xa[0] = x0.x; xa[1] = x0.y; xa[2] = x0.z; xa[3] = x0.w;
            xa[4] = x1.x; xa[5] = x1.y; xa[6] = x1.z; xa[7] = x1.w;
            wb[0] = w0.x; wb[1] = w0.y; wb[2] = w0.z; wb[3] = w0.w;
            wb[4] = w1.x; wb[5] = w1.y; wb[6] = w1.z; wb[7] = w1.w;
        }
        bfrag Ah, Al, Bh, Bl;
        cvt_hilo(xa, Ah, Al);
        cvt_hilo(wb, Bh, Bl);
        acc = __builtin_amdgcn_mfma_f32_32x32x16_bf16(Ah, Bh, acc, 0, 0, 0);
        acc = __builtin_amdgcn_mfma_f32_32x32x16_bf16(Ah, Bl, acc, 0, 0, 0);
        acc = __builtin_amdgcn_mfma_f32_32x32x16_bf16(Al, Bh, acc, 0, 0, 0);
    }

    // epilogue: C/D layout col=c, row=(g&3)+8*(g>>2)+4*h
    const float C2 = -0.0239861701969175f; // -2*ln(10000)/768
    const int n = n0 + 32 * wn + c;
    #pragma unroll
    for (int g = 0; g < 16; g++) {
        const int rr = (g & 3) + 8 * (g >> 2) + 4 * h;
        const int m  = m0 + 32 * wm + rr;
        if (m >= NM) continue;
        float v = acc[g] + bias[n];
        if (z < 2) {
            const int bpos = m / NS;  // pe indexed by BATCH position (faithful)
            const float ang = (float)bpos * expf((float)(n >> 1) * C2);
            v += (n & 1) ? cosf(ang) : sinf(ang);
        }
        out[(size_t)m * ND + n] = v;
    }
}

// ---------------- Kernel 2: scores+softmax+ctx, and Ag = gamma*Q_trans -----
__global__ __launch_bounds__(64) void attn(
    const float* __restrict__ Q, const float* __restrict__ K,
    const float* __restrict__ V,
    const float* __restrict__ lin_w, const float* __restrict__ lin_b,
    float* __restrict__ Ag, float* __restrict__ ctx_out)
{
    const int bq = blockIdx.x;
    const int b = bq / NS, q = bq % NS;
    const int lane = threadIdx.x;

    const float* Qr = Q + (b * NS + q) * ND;
    float qv[12];
    #pragma unroll
    for (int m = 0; m < 12; m++) qv[m] = Qr[m * 64 + lane];

    // scores: lane k ends up holding score[k]*8
    float mysc = 0.f;
    for (int k = 0; k < NS; k++) {
        const float* Kr = K + (b * NS + k) * ND;
        float s = 0.f;
        #pragma unroll
        for (int m = 0; m < 12; m++) s += qv[m] * Kr[m * 64 + lane];
        #pragma unroll
        for (int off = 32; off; off >>= 1) s += __shfl_xor(s, off);
        if (lane == k) mysc = s * 8.f;
    }
    // Q_trans row q: lane j holds Qt[j]; write Ag = gamma*(Qt + lin_b)
    float myqt = 0.f;
    for (int j = 0; j < NS; j++) {
        const float* Lr = lin_w + j * ND;
        float s = 0.f;
        #pragma unroll
        for (int m = 0; m < 12; m++) s += qv[m] * Lr[m * 64 + lane];
        #pragma unroll
        for (int off = 32; off; off >>= 1) s += __shfl_xor(s, off);
        if (lane == j) myqt = s;
    }
    if (lane < NS)
        Ag[b * (NS * NS) + q * NS + lane] = GAMA * (myqt + lin_b[lane]);

    // softmax over lanes 0..49
    const float sc = (lane < NS) ? mysc : -INFINITY;
    float mx = sc;
    #pragma unroll
    for (int off = 32; off; off >>= 1) mx = fmaxf(mx, __shfl_xor(mx, off));
    const float e = (lane < NS) ? expf(sc - mx) : 0.f;
    float sum = e;
    #pragma unroll
    for (int off = 32; off; off >>= 1) sum += __shfl_xor(sum, off);
    const float p = e / sum;

    // ctx row = sum_k p_k * V[b,k,:]
    float acc[12];
    #pragma unroll
    for (int m = 0; m < 12; m++) acc[m] = 0.f;
    for (int k = 0; k < NS; k++) {
        const float pk = __shfl(p, k);
        const float* Vr = V + (b * NS + k) * ND;
        #pragma unroll
        for (int m = 0; m < 12; m++) acc[m] += pk * Vr[m * 64 + lane];
    }
    float* Cr = ctx_out + (b * NS + q) * ND;
    #pragma unroll
    for (int m = 0; m < 12; m++) Cr[m * 64 + lane] = acc[m];
}

// ---------------- Kernel 3: gamma-decay recurrence via MFMA ----------------
// (R13 version, unchanged — fat VMEM through LDS layout-transpose; ~105us.)
__global__ __launch_bounds__(64, 1) void recur(
    const float* __restrict__ Ag, const float* __restrict__ ctx,
    float* __restrict__ rec)
{
    const int blk   = blockIdx.x;          // 0..1103
    const int b     = blk / 24;
    const int chunk = blk - b * 24;        // 0..23 -> 32 cols
    const int l     = threadIdx.x;
    const int c     = l & 31;
    const int h     = l >> 5;
    const int d0    = chunk * 32;
    const int srow  = l >> 3;              // 0..7   (fat-op tile row)
    const int scol  = (l & 7) * 4;         // 0,4..28 (fat-op tile col)

    __shared__ float Sf[64 * 32];          // state f32, 8 KB
    __shared__ float Cx[64 * 32];          // ctx staging, 8 KB

    // ---- A fragments (hi/lo), ONCE, straight from global (L2-resident) ----
    const float* __restrict__ Ab = Ag + b * (NS * NS);
    bfrag Ah[2][4], Al[2][4];
    #pragma unroll
    for (int mt = 0; mt < 2; mt++) {
        const int row = 32 * mt + c;
        const bool rok = row < NS;
        const float* __restrict__ Arow = Ab + row * NS;
        #pragma unroll
        for (int kt = 0; kt < 4; kt++) {
            FragU uh, ul;
            #pragma unroll
            for (int t = 0; t < 4; t++) {
                const int k0 = 16 * kt + 8 * h + 2 * t;
                const float e = (rok && k0     < NS) ? Arow[k0]     : 0.f;
                const float o = (rok && k0 + 1 < NS) ? Arow[k0 + 1] : 0.f;
                const unsigned ue = __float_as_uint(e), uo = __float_as_uint(o);
                uh.u[t] = (ue >> 16) | (uo & 0xFFFF0000u);
                const float re = e - __uint_as_float(ue & 0xFFFF0000u);
                const float ro = o - __uint_as_float(uo & 0xFFFF0000u);
                ul.u[t] = (__float_as_uint(re) >> 16) | (__float_as_uint(ro) & 0xFFFF0000u);
            }
            Ah[mt][kt] = uh.f; Al[mt][kt] = ul.f;
        }
    }

    // ---- zero pad rows 48..63 of both LDS arrays ----
    {
        const float4 z = make_float4(0.f, 0.f, 0.f, 0.f);
        *reinterpret_cast<float4*>(&Cx[(48 + srow) * 32 + scol]) = z;
        *reinterpret_cast<float4*>(&Cx[(56 + srow) * 32 + scol]) = z;
        *reinterpret_cast<float4*>(&Sf[(48 + srow) * 32 + scol]) = z;
        *reinterpret_cast<float4*>(&Sf[(56 + srow) * 32 + scol]) = z;
    }

    // ---- step 0: load ctx_0 (fat), store rec_0 (fat), seed Sf ----
    float4 creg[7];
    #pragma unroll
    for (int it = 0; it < 7; ++it) creg[it] = make_float4(0.f, 0.f, 0.f, 0.f);
    {
        const float* __restrict__ src = ctx + d0;
        #pragma unroll
        for (int it = 0; it < 7; ++it) {
            const int r = it * 8 + srow;
            if (r < NS)
                creg[it] = *reinterpret_cast<const float4*>(&src[(size_t)r * ND + scol]);
        }
        float* __restrict__ r0 = rec + (size_t)b * NS * ND + d0;
        #pragma unroll
        for (int it = 0; it < 7; ++it) {
            const int r = it * 8 + srow;
            if (r < NS) {
                *reinterpret_cast<float4*>(&Sf[r * 32 + scol]) = creg[it];
                *reinterpret_cast<float4*>(&r0[(size_t)r * ND + scol]) = creg[it];
            }
        }
    }
    // ---- load ctx_1 -> cregs (consumed at step 1) ----
    {
        const float* __restrict__ src = ctx + (size_t)NS * ND + d0;
        #pragma unroll
        for (int it = 0; it < 7; ++it) {
            const int r = it * 8 + srow;
            if (r < NS)
                creg[it] = *reinterpret_cast<const float4*>(&src[(size_t)r * ND + scol]);
        }
    }

    // ---- steps 1..45 ----
    for (int i = 1; i < NB; ++i) {
        // [A] flush cregs (ctx_i) -> Cx
        #pragma unroll
        for (int it = 0; it < 7; ++it) {
            const int r = it * 8 + srow;
            if (r < NS)
                *reinterpret_cast<float4*>(&Cx[r * 32 + scol]) = creg[it];
        }
        // [B] issue fat loads of ctx_{i+1}
        if (i + 1 < NB) {
            const float* __restrict__ src = ctx + (size_t)(i + 1) * NS * ND + d0;
            #pragma unroll
            for (int it = 0; it < 7; ++it) {
                const int r = it * 8 + srow;
                if (r < NS)
                    creg[it] = *reinterpret_cast<const float4*>(&src[(size_t)r * ND + scol]);
            }
        }
        // [C] acc init from Cx (C-layout; pad rows read exact 0)
        f32x16 acc[2];
        #pragma unroll
        for (int mt = 0; mt < 2; mt++)
            #pragma unroll
            for (int g = 0; g < 16; g++) {
                const int rg = 32 * mt + (g & 3) + 8 * (g >> 2) + 4 * h;
                acc[mt][g] = Cx[rg * 32 + c];
            }
        // [D] B-frags of s_{i-1} from Sf (pack hi/lo)
        bfrag Bh[4], Bl[4];
        #pragma unroll
        for (int kt = 0; kt < 4; kt++) {
            float f[8];
            #pragma unroll
            for (int j = 0; j < 8; j++)
                f[j] = Sf[(16 * kt + 8 * h + j) * 32 + c];
            FragU uh, ul;
            #pragma unroll
            for (int t = 0; t < 4; t++) {
                const unsigned b0 = __float_as_uint(f[2 * t]);
                const unsigned b1 = __float_as_uint(f[2 * t + 1]);
                uh.u[t] = (b0 >> 16) | (b1 & 0xFFFF0000u);
                const float r0f = f[2 * t]     - __uint_as_float(b0 & 0xFFFF0000u);
                const float r1f = f[2 * t + 1] - __uint_as_float(b1 & 0xFFFF0000u);
                ul.u[t] = (__float_as_uint(r0f) >> 16) | (__float_as_uint(r1f) & 0xFFFF0000u);
            }
            Bh[kt] = uh.f; Bl[kt] = ul.f;
        }
        // [E] 12 MFMA per mt: hi*hi, hi*lo, lo*hi
        #pragma unroll
        for (int mt = 0; mt < 2; mt++) {
            f32x16 a = acc[mt];
            #pragma unroll
            for (int kt = 0; kt < 4; kt++)
                a = __builtin_amdgcn_mfma_f32_32x32x16_bf16(Ah[mt][kt], Bh[kt], a, 0, 0, 0);
            #pragma unroll
            for (int kt = 0; kt < 4; kt++)
                a = __builtin_amdgcn_mfma_f32_32x32x16_bf16(Ah[mt][kt], Bl[kt], a, 0, 0, 0);
            #pragma unroll
            for (int kt = 0; kt < 4; kt++)
                a = __builtin_amdgcn_mfma_f32_32x32x16_bf16(Al[mt][kt], Bh[kt], a, 0, 0, 0);
            acc[mt] = a;
        }
        // [F] acc -> Sf (all 64 rows; pad rows exact 0)
        #pragma unroll
        for (int mt = 0; mt < 2; mt++)
            #pragma unroll
            for (int g = 0; g < 16; g++) {
                const int rg = 32 * mt + (g & 3) + 8 * (g >> 2) + 4 * h;
                Sf[rg * 32 + c] = acc[mt][g];
            }
        // [G]+[H] fat read-back + fat store of rec_i
        float* __restrict__ reci = rec + (size_t)(i * NB + b) * NS * ND + d0;
        #pragma unroll
        for (int it = 0; it < 7; ++it) {
            const int r = it * 8 + srow;
            if (r < NS) {
                const float4 v = *reinterpret_cast<const float4*>(&Sf[r * 32 + scol]);
                *reinterpret_cast<float4*>(&reci[(size_t)r * ND + scol]) = v;
            }
        }
    }
}

extern "C" void kernel_launch(void* const* d_in, const int* in_sizes, int n_in,
                              void* d_out, int out_size, void* d_ws, size_t ws_size,
                              hipStream_t stream) {
    const float* text_emb = (const float*)d_in[0];
    const float* emb      = (const float*)d_in[1];
    const float* Wq = (const float*)d_in[2]; const float* bq = (const float*)d_in[3];
    const float* Wk = (const float*)d_in[4]; const float* bk = (const float*)d_in[5];
    const float* Wv = (const float*)d_in[6]; const float* bv = (const float*)d_in[7];
    const float* lw = (const float*)d_in[8]; const float* lb = (const float*)d_in[9];

    float* out = (float*)d_out;
    float* ctx = out;                          // [46,50,768]
    float* rec = out + NB * NS * ND;           // [46,46,50,768]

    float* ws = (float*)d_ws;                  // needs 21.7 MB
    float* Q  = ws;
    float* K  = Q + NB * NS * ND;
    float* V  = K + NB * NS * ND;
    float* Ag = V + NB * NS * ND;              // gamma * Q_trans, [46,50,50]

    qkv_gemm<<<dim3(36, 12, 3), 256, 0, stream>>>(text_emb, emb, Wq, bq, Wk, bk, Wv, bv, Q, K, V);
    attn<<<dim3(NM), 64, 0, stream>>>(Q, K, V, lw, lb, Ag, ctx);
    recur<<<dim3(1104), 64, 0, stream>>>(Ag, ctx, rec);
}

// Round 15
// 271.747 us; speedup vs baseline: 1.9145x; 1.0510x over previous
//
#include <hip/hip_runtime.h>
#include <math.h>

#define NB 46
#define NS 50
#define ND 768
#define GAMA 0.96875f
#define NM 2300   // NB*NS rows

using bfrag  = __attribute__((ext_vector_type(8))) short;   // 8 bf16 = 4 VGPRs
using f32x16 = __attribute__((ext_vector_type(16))) float;  // 32x32 acc

union FragU { unsigned u[4]; bfrag f; };

// hi/lo bf16 split of 8 f32 (truncation; combined ~16-bit mantissa)
__device__ __forceinline__ void cvt_hilo(const float f[8], bfrag& fh, bfrag& fl)
{
    FragU uh, ul;
    #pragma unroll
    for (int t = 0; t < 4; t++) {
        const unsigned b0 = __float_as_uint(f[2 * t]);
        const unsigned b1 = __float_as_uint(f[2 * t + 1]);
        uh.u[t] = (b0 >> 16) | (b1 & 0xFFFF0000u);
        const float r0 = f[2 * t]     - __uint_as_float(b0 & 0xFFFF0000u);
        const float r1 = f[2 * t + 1] - __uint_as_float(b1 & 0xFFFF0000u);
        ul.u[t] = (__float_as_uint(r0) >> 16) | (__float_as_uint(r1) & 0xFFFF0000u);
    }
    fh = uh.f; fl = ul.f;
}

// ---------------- Kernel 1: QKV projections via MFMA (hi/lo bf16) ---------
// (R14 version, unchanged.)
__global__ __launch_bounds__(256) void qkv_gemm(
    const float* __restrict__ text_emb, const float* __restrict__ emb,
    const float* __restrict__ Wq, const float* __restrict__ bq,
    const float* __restrict__ Wk, const float* __restrict__ bk,
    const float* __restrict__ Wv, const float* __restrict__ bv,
    float* __restrict__ Q, float* __restrict__ K, float* __restrict__ V)
{
    const int z = blockIdx.z;
    const float* X    = (z == 0) ? text_emb : emb;
    const float* W    = (z == 0) ? Wq : (z == 1) ? Wk : Wv;
    const float* bias = (z == 0) ? bq : (z == 1) ? bk : bv;
    float* out        = (z == 0) ? Q  : (z == 1) ? K  : V;

    const int tid = threadIdx.x;
    const int w   = tid >> 6;           // wave 0..3
    const int l   = tid & 63;
    const int c   = l & 31;
    const int h   = l >> 5;
    const int wm  = w >> 1, wn = w & 1; // quadrant
    const int m0  = blockIdx.x * 64, n0 = blockIdx.y * 64;

    const int mrow = m0 + 32 * wm + c;
    const int nrow = n0 + 32 * wn + c;
    const bool mok = mrow < NM;
    const float* __restrict__ Xr = X + (size_t)(mok ? mrow : 0) * ND + 8 * h;
    const float* __restrict__ Wr = W + (size_t)nrow * ND + 8 * h;

    f32x16 acc;
    #pragma unroll
    for (int g = 0; g < 16; g++) acc[g] = 0.f;

    #pragma unroll 2
    for (int kk = 0; kk < ND; kk += 16) {
        float xa[8], wb[8];
        {
            const float4 x0 = *reinterpret_cast<const float4*>(Xr + kk);
            const float4 x1 = *reinterpret_cast<const float4*>(Xr + kk + 4);
            const float4 w0 = *reinterpret_cast<const float4*>(Wr + kk);
            const float4 w1 = *reinterpret_cast<const float4*>(Wr + kk + 4);
            xa[0] = x0.x; xa[1] = x0.y; xa[2] = x0.z; xa[3] = x0.w;
            xa[4] = x1.x; xa[5] = x1.y; xa[6] = x1.z; xa[7] = x1.w;
            wb[0] = w0.x; wb[1] = w0.y; wb[2] = w0.z; wb[3] = w0.w;
            wb[4] = w1.x; wb[5] = w1.y; wb[6] = w1.z; wb[7] = w1.w;
        }
        bfrag Ah, Al, Bh, Bl;
        cvt_hilo(xa, Ah, Al);
        cvt_hilo(wb, Bh, Bl);
        acc = __builtin_amdgcn_mfma_f32_32x32x16_bf16(Ah, Bh, acc, 0, 0, 0);
        acc = __builtin_amdgcn_mfma_f32_32x32x16_bf16(Ah, Bl, acc, 0, 0, 0);
        acc = __builtin_amdgcn_mfma_f32_32x32x16_bf16(Al, Bh, acc, 0, 0, 0);
    }

    const float C2 = -0.0239861701969175f; // -2*ln(10000)/768
    const int n = n0 + 32 * wn + c;
    #pragma unroll
    for (int g = 0; g < 16; g++) {
        const int rr = (g & 3) + 8 * (g >> 2) + 4 * h;
        const int m  = m0 + 32 * wm + rr;
        if (m >= NM) continue;
        float v = acc[g] + bias[n];
        if (z < 2) {
            const int bpos = m / NS;  // pe indexed by BATCH position (faithful)
            const float ang = (float)bpos * expf((float)(n >> 1) * C2);
            v += (n & 1) ? cosf(ang) : sinf(ang);
        }
        out[(size_t)m * ND + n] = v;
    }
}

// ---------------- Kernel 2: attention via MFMA, one block per b ------------
// R14 analysis: the scalar-load shfl-reduce attn is the remaining ~100+us.
// Per b: S = 8*(Q@K^T) [50x50], Qt = Q@lin_w^T [50x50], P = softmax(S),
// ctx = P@V [50x768]. 46 blocks x 256 threads (4 waves).
// Pass 1 (fused): waves K-split (192 floats each); per k-step build hi/lo
// frags of Q/K/lin_w, 24 MFMA; partial tiles -> LDS (stride-68 rows),
// cross-wave reduce (x8 applied to S here). Softmax in f32 (rows<50);
// P cols/rows 50-63 zeroed/never-stored (pad-key hygiene). Ag = gama*
// (Qt+lin_b) straight from the reduced tile. Pass 2: PV with hoisted P
// A-frags (hi/lo) and lane-coalesced V column loads. Frag conventions
// identical to R9/R13/R14 (verified-passing).
__global__ __launch_bounds__(256, 1) void attn(
    const float* __restrict__ Q, const float* __restrict__ K,
    const float* __restrict__ V,
    const float* __restrict__ lin_w, const float* __restrict__ lin_b,
    float* __restrict__ Ag, float* __restrict__ ctx_out)
{
    const int b   = blockIdx.x;
    const int tid = threadIdx.x;
    const int w   = tid >> 6;          // wave 0..3
    const int l   = tid & 63;
    const int c   = l & 31;
    const int h   = l >> 5;

    __shared__ float Lsh[9 * 64 * 68];           // 153 KB
    float* SP = Lsh;                              // 4 partial S tiles
    float* QP = Lsh + 4 * 64 * 68;                // 4 partial Qt tiles
    float* Pf = Lsh + 8 * 64 * 68;                // P

    const float* __restrict__ Qb = Q + (size_t)b * NS * ND;
    const float* __restrict__ Kb = K + (size_t)b * NS * ND;
    const float* __restrict__ Vb = V + (size_t)b * NS * ND;

    // ---- pass 1: fused S & Qt partials over this wave's K-slice ----
    f32x16 accS[2][2], accQ[2][2];
    #pragma unroll
    for (int mt = 0; mt < 2; mt++)
        #pragma unroll
        for (int nt = 0; nt < 2; nt++)
            #pragma unroll
            for (int g = 0; g < 16; g++) { accS[mt][nt][g] = 0.f; accQ[mt][nt][g] = 0.f; }

    const int ks = w * 192;
    for (int kt = 0; kt < 12; ++kt) {
        const int ko = ks + kt * 16 + 8 * h;
        bfrag Qh[2], Ql[2], Kh[2], Kl[2], Wh[2], Wl[2];
        #pragma unroll
        for (int mt = 0; mt < 2; mt++) {
            const int row = 32 * mt + c;
            const int r = (row < NS) ? row : 0;
            float f[8];
            {
                const float4 a0 = *reinterpret_cast<const float4*>(&Qb[(size_t)r * ND + ko]);
                const float4 a1 = *reinterpret_cast<const float4*>(&Qb[(size_t)r * ND + ko + 4]);
                f[0]=a0.x; f[1]=a0.y; f[2]=a0.z; f[3]=a0.w; f[4]=a1.x; f[5]=a1.y; f[6]=a1.z; f[7]=a1.w;
            }
            cvt_hilo(f, Qh[mt], Ql[mt]);
            {
                const float4 a0 = *reinterpret_cast<const float4*>(&Kb[(size_t)r * ND + ko]);
                const float4 a1 = *reinterpret_cast<const float4*>(&Kb[(size_t)r * ND + ko + 4]);
                f[0]=a0.x; f[1]=a0.y; f[2]=a0.z; f[3]=a0.w; f[4]=a1.x; f[5]=a1.y; f[6]=a1.z; f[7]=a1.w;
            }
            cvt_hilo(f, Kh[mt], Kl[mt]);
            {
                const float4 a0 = *reinterpret_cast<const float4*>(&lin_w[(size_t)r * ND + ko]);
                const float4 a1 = *reinterpret_cast<const float4*>(&lin_w[(size_t)r * ND + ko + 4]);
                f[0]=a0.x; f[1]=a0.y; f[2]=a0.z; f[3]=a0.w; f[4]=a1.x; f[5]=a1.y; f[6]=a1.z; f[7]=a1.w;
            }
            cvt_hilo(f, Wh[mt], Wl[mt]);
        }
        #pragma unroll
        for (int mt = 0; mt < 2; mt++)
            #pragma unroll
            for (int nt = 0; nt < 2; nt++) {
                f32x16 a = accS[mt][nt];
                a = __builtin_amdgcn_mfma_f32_32x32x16_bf16(Qh[mt], Kh[nt], a, 0, 0, 0);
                a = __builtin_amdgcn_mfma_f32_32x32x16_bf16(Qh[mt], Kl[nt], a, 0, 0, 0);
                a = __builtin_amdgcn_mfma_f32_32x32x16_bf16(Ql[mt], Kh[nt], a, 0, 0, 0);
                accS[mt][nt] = a;
                f32x16 q = accQ[mt][nt];
                q = __builtin_amdgcn_mfma_f32_32x32x16_bf16(Qh[mt], Wh[nt], q, 0, 0, 0);
                q = __builtin_amdgcn_mfma_f32_32x32x16_bf16(Qh[mt], Wl[nt], q, 0, 0, 0);
                q = __builtin_amdgcn_mfma_f32_32x32x16_bf16(Ql[mt], Wh[nt], q, 0, 0, 0);
                accQ[mt][nt] = q;
            }
    }

    // write partials (stride-68 rows: bank = (4*rg + col) % 32, conflict-free)
    {
        float* SPw = SP + w * (64 * 68);
        float* QPw = QP + w * (64 * 68);
        #pragma unroll
        for (int mt = 0; mt < 2; mt++)
            #pragma unroll
            for (int nt = 0; nt < 2; nt++)
                #pragma unroll
                for (int g = 0; g < 16; g++) {
                    const int rg  = 32 * mt + (g & 3) + 8 * (g >> 2) + 4 * h;
                    const int col = 32 * nt + c;
                    SPw[rg * 68 + col] = accS[mt][nt][g];
                    QPw[rg * 68 + col] = accQ[mt][nt][g];
                }
    }
    __syncthreads();

    // reduce partials: S gets the x8 scaling; results land in SP[0]/QP[0]
    {
        const int r  = tid >> 2;
        const int cg = (tid & 3) * 16;
        #pragma unroll
        for (int q4 = 0; q4 < 4; ++q4) {
            const int off = r * 68 + cg + q4 * 4;
            float4 s0 = *reinterpret_cast<const float4*>(&SP[off]);
            float4 s1 = *reinterpret_cast<const float4*>(&SP[64 * 68 + off]);
            float4 s2 = *reinterpret_cast<const float4*>(&SP[2 * 64 * 68 + off]);
            float4 s3 = *reinterpret_cast<const float4*>(&SP[3 * 64 * 68 + off]);
            float4 r4;
            r4.x = 8.f * ((s0.x + s1.x) + (s2.x + s3.x));
            r4.y = 8.f * ((s0.y + s1.y) + (s2.y + s3.y));
            r4.z = 8.f * ((s0.z + s1.z) + (s2.z + s3.z));
            r4.w = 8.f * ((s0.w + s1.w) + (s2.w + s3.w));
            *reinterpret_cast<float4*>(&SP[off]) = r4;
            float4 t0 = *reinterpret_cast<const float4*>(&QP[off]);
            float4 t1 = *reinterpret_cast<const float4*>(&QP[64 * 68 + off]);
            float4 t2 = *reinterpret_cast<const float4*>(&QP[2 * 64 * 68 + off]);
            float4 t3 = *reinterpret_cast<const float4*>(&QP[3 * 64 * 68 + off]);
            float4 u4;
            u4.x = (t0.x + t1.x) + (t2.x + t3.x);
            u4.y = (t0.y + t1.y) + (t2.y + t3.y);
            u4.z = (t0.z + t1.z) + (t2.z + t3.z);
            u4.w = (t0.w + t1.w) + (t2.w + t3.w);
            *reinterpret_cast<float4*>(&QP[off]) = u4;
        }
    }
    __syncthreads();

    // softmax (rows < 50) + pad-zeroing of P cols 50..63
    if (tid < NS) {
        const float* Sr = SP + tid * 68;
        float mx = -INFINITY;
        for (int c2 = 0; c2 < NS; ++c2) mx = fmaxf(mx, Sr[c2]);
        float sum = 0.f;
        for (int c2 = 0; c2 < NS; ++c2) {
            const float e = expf(Sr[c2] - mx);
            Pf[tid * 68 + c2] = e;
            sum += e;
        }
        const float inv = 1.f / sum;
        for (int c2 = 0; c2 < NS; ++c2) Pf[tid * 68 + c2] *= inv;
        for (int c2 = NS; c2 < 64; ++c2) Pf[tid * 68 + c2] = 0.f;
    }
    // Ag = gama * (Qt + lin_b)
    for (int e = tid; e < NS * NS; e += 256) {
        const int r = e / NS, cc = e - r * NS;
        Ag[b * (NS * NS) + e] = GAMA * (QP[r * 68 + cc] + lin_b[cc]);
    }
    __syncthreads();

    // ---- pass 2: ctx = P @ V, 3 chunks of 64 cols per wave ----
    bfrag Ph[2][4], Pl[2][4];
    #pragma unroll
    for (int mt = 0; mt < 2; mt++)
        #pragma unroll
        for (int kt = 0; kt < 4; kt++) {
            float f[8];
            #pragma unroll
            for (int j = 0; j < 8; j++)
                f[j] = Pf[(32 * mt + c) * 68 + kt * 16 + 8 * h + j];
            cvt_hilo(f, Ph[mt][kt], Pl[mt][kt]);
        }

    for (int j3 = 0; j3 < 3; ++j3) {
        const int dbase = (w * 3 + j3) * 64;
        f32x16 accC[2][2];
        #pragma unroll
        for (int mt = 0; mt < 2; mt++)
            #pragma unroll
            for (int nt = 0; nt < 2; nt++)
                #pragma unroll
                for (int g = 0; g < 16; g++) accC[mt][nt][g] = 0.f;

        #pragma unroll
        for (int nt = 0; nt < 2; nt++) {
            const int d = dbase + 32 * nt + c;
            #pragma unroll
            for (int kt = 0; kt < 4; kt++) {
                float f[8];
                #pragma unroll
                for (int j = 0; j < 8; j++) {
                    const int k2 = kt * 16 + 8 * h + j;
                    f[j] = (k2 < NS) ? Vb[(size_t)k2 * ND + d] : 0.f;
                }
                bfrag Bh, Bl;
                cvt_hilo(f, Bh, Bl);
                #pragma unroll
                for (int mt = 0; mt < 2; mt++) {
                    f32x16 a = accC[mt][nt];
                    a = __builtin_amdgcn_mfma_f32_32x32x16_bf16(Ph[mt][kt], Bh, a, 0, 0, 0);
                    a = __builtin_amdgcn_mfma_f32_32x32x16_bf16(Ph[mt][kt], Bl, a, 0, 0, 0);
                    a = __builtin_amdgcn_mfma_f32_32x32x16_bf16(Pl[mt][kt], Bh, a, 0, 0, 0);
                    accC[mt][nt] = a;
                }
            }
        }
        #pragma unroll
        for (int mt = 0; mt < 2; mt++)
            #pragma unroll
            for (int nt = 0; nt < 2; nt++)
                #pragma unroll
                for (int g = 0; g < 16; g++) {
                    const int rg = 32 * mt + (g & 3) + 8 * (g >> 2) + 4 * h;
                    if (rg < NS)
                        ctx_out[((size_t)b * NS + rg) * ND + dbase + 32 * nt + c] = accC[mt][nt][g];
                }
    }
}

// ---------------- Kernel 3: gamma-decay recurrence via MFMA ----------------
// (R13 version, unchanged — fat VMEM through LDS layout-transpose; ~104us.)
__global__ __launch_bounds__(64, 1) void recur(
    const float* __restrict__ Ag, const float* __restrict__ ctx,
    float* __restrict__ rec)
{
    const int blk   = blockIdx.x;          // 0..1103
    const int b     = blk / 24;
    const int chunk = blk - b * 24;        // 0..23 -> 32 cols
    const int l     = threadIdx.x;
    const int c     = l & 31;
    const int h     = l >> 5;
    const int d0    = chunk * 32;
    const int srow  = l >> 3;              // 0..7
    const int scol  = (l & 7) * 4;         // 0,4..28

    __shared__ float Sf[64 * 32];
    __shared__ float Cx[64 * 32];

    const float* __restrict__ Ab = Ag + b * (NS * NS);
    bfrag Ah[2][4], Al[2][4];
    #pragma unroll
    for (int mt = 0; mt < 2; mt++) {
        const int row = 32 * mt + c;
        const bool rok = row < NS;
        const float* __restrict__ Arow = Ab + row * NS;
        #pragma unroll
        for (int kt = 0; kt < 4; kt++) {
            FragU uh, ul;
            #pragma unroll
            for (int t = 0; t < 4; t++) {
                const int k0 = 16 * kt + 8 * h + 2 * t;
                const float e = (rok && k0     < NS) ? Arow[k0]     : 0.f;
                const float o = (rok && k0 + 1 < NS) ? Arow[k0 + 1] : 0.f;
                const unsigned ue = __float_as_uint(e), uo = __float_as_uint(o);
                uh.u[t] = (ue >> 16) | (uo & 0xFFFF0000u);
                const float re = e - __uint_as_float(ue & 0xFFFF0000u);
                const float ro = o - __uint_as_float(uo & 0xFFFF0000u);
                ul.u[t] = (__float_as_uint(re) >> 16) | (__float_as_uint(ro) & 0xFFFF0000u);
            }
            Ah[mt][kt] = uh.f; Al[mt][kt] = ul.f;
        }
    }

    {
        const float4 z = make_float4(0.f, 0.f, 0.f, 0.f);
        *reinterpret_cast<float4*>(&Cx[(48 + srow) * 32 + scol]) = z;
        *reinterpret_cast<float4*>(&Cx[(56 + srow) * 32 + scol]) = z;
        *reinterpret_cast<float4*>(&Sf[(48 + srow) * 32 + scol]) = z;
        *reinterpret_cast<float4*>(&Sf[(56 + srow) * 32 + scol]) = z;
    }

    float4 creg[7];
    #pragma unroll
    for (int it = 0; it < 7; ++it) creg[it] = make_float4(0.f, 0.f, 0.f, 0.f);
    {
        const float* __restrict__ src = ctx + d0;
        #pragma unroll
        for (int it = 0; it < 7; ++it) {
            const int r = it * 8 + srow;
            if (r < NS)
                creg[it] = *reinterpret_cast<const float4*>(&src[(size_t)r * ND + scol]);
        }
        float* __restrict__ r0 = rec + (size_t)b * NS * ND + d0;
        #pragma unroll
        for (int it = 0; it < 7; ++it) {
            const int r = it * 8 + srow;
            if (r < NS) {
                *reinterpret_cast<float4*>(&Sf[r * 32 + scol]) = creg[it];
                *reinterpret_cast<float4*>(&r0[(size_t)r * ND + scol]) = creg[it];
            }
        }
    }
    {
        const float* __restrict__ src = ctx + (size_t)NS * ND + d0;
        #pragma unroll
        for (int it = 0; it < 7; ++it) {
            const int r = it * 8 + srow;
            if (r < NS)
                creg[it] = *reinterpret_cast<const float4*>(&src[(size_t)r * ND + scol]);
        }
    }

    for (int i = 1; i < NB; ++i) {
        #pragma unroll
        for (int it = 0; it < 7; ++it) {
            const int r = it * 8 + srow;
            if (r < NS)
                *reinterpret_cast<float4*>(&Cx[r * 32 + scol]) = creg[it];
        }
        if (i + 1 < NB) {
            const float* __restrict__ src = ctx + (size_t)(i + 1) * NS * ND + d0;
            #pragma unroll
            for (int it = 0; it < 7; ++it) {
                const int r = it * 8 + srow;
                if (r < NS)
                    creg[it] = *reinterpret_cast<const float4*>(&src[(size_t)r * ND + scol]);
            }
        }
        f32x16 acc[2];
        #pragma unroll
        for (int mt = 0; mt < 2; mt++)
            #pragma unroll
            for (int g = 0; g < 16; g++) {
                const int rg = 32 * mt + (g & 3) + 8 * (g >> 2) + 4 * h;
                acc[mt][g] = Cx[rg * 32 + c];
            }
        bfrag Bh[4], Bl[4];
        #pragma unroll
        for (int kt = 0; kt < 4; kt++) {
            float f[8];
            #pragma unroll
            for (int j = 0; j < 8; j++)
                f[j] = Sf[(16 * kt + 8 * h + j) * 32 + c];
            FragU uh, ul;
            #pragma unroll
            for (int t = 0; t < 4; t++) {
                const unsigned b0 = __float_as_uint(f[2 * t]);
                const unsigned b1 = __float_as_uint(f[2 * t + 1]);
                uh.u[t] = (b0 >> 16) | (b1 & 0xFFFF0000u);
                const float r0f = f[2 * t]     - __uint_as_float(b0 & 0xFFFF0000u);
                const float r1f = f[2 * t + 1] - __uint_as_float(b1 & 0xFFFF0000u);
                ul.u[t] = (__float_as_uint(r0f) >> 16) | (__float_as_uint(r1f) & 0xFFFF0000u);
            }
            Bh[kt] = uh.f; Bl[kt] = ul.f;
        }
        #pragma unroll
        for (int mt = 0; mt < 2; mt++) {
            f32x16 a = acc[mt];
            #pragma unroll
            for (int kt = 0; kt < 4; kt++)
                a = __builtin_amdgcn_mfma_f32_32x32x16_bf16(Ah[mt][kt], Bh[kt], a, 0, 0, 0);
            #pragma unroll
            for (int kt = 0; kt < 4; kt++)
                a = __builtin_amdgcn_mfma_f32_32x32x16_bf16(Ah[mt][kt], Bl[kt], a, 0, 0, 0);
            #pragma unroll
            for (int kt = 0; kt < 4; kt++)
                a = __builtin_amdgcn_mfma_f32_32x32x16_bf16(Al[mt][kt], Bh[kt], a, 0, 0, 0);
            acc[mt] = a;
        }
        #pragma unroll
        for (int mt = 0; mt < 2; mt++)
            #pragma unroll
            for (int g = 0; g < 16; g++) {
                const int rg = 32 * mt + (g & 3) + 8 * (g >> 2) + 4 * h;
                Sf[rg * 32 + c] = acc[mt][g];
            }
        float* __restrict__ reci = rec + (size_t)(i * NB + b) * NS * ND + d0;
        #pragma unroll
        for (int it = 0; it < 7; ++it) {
            const int r = it * 8 + srow;
            if (r < NS) {
                const float4 v = *reinterpret_cast<const float4*>(&Sf[r * 32 + scol]);
                *reinterpret_cast<float4*>(&reci[(size_t)r * ND + scol]) = v;
            }
        }
    }
}

extern "C" void kernel_launch(void* const* d_in, const int* in_sizes, int n_in,
                              void* d_out, int out_size, void* d_ws, size_t ws_size,
                              hipStream_t stream) {
    const float* text_emb = (const float*)d_in[0];
    const float* emb      = (const float*)d_in[1];
    const float* Wq = (const float*)d_in[2]; const float* bq = (const float*)d_in[3];
    const float* Wk = (const float*)d_in[4]; const float* bk = (const float*)d_in[5];
    const float* Wv = (const float*)d_in[6]; const float* bv = (const float*)d_in[7];
    const float* lw = (const float*)d_in[8]; const float* lb = (const float*)d_in[9];

    float* out = (float*)d_out;
    float* ctx = out;                          // [46,50,768]
    float* rec = out + NB * NS * ND;           // [46,46,50,768]

    float* ws = (float*)d_ws;                  // needs 21.7 MB
    float* Q  = ws;
    float* K  = Q + NB * NS * ND;
    float* V  = K + NB * NS * ND;
    float* Ag = V + NB * NS * ND;              // gamma * Q_trans, [46,50,50]

    qkv_gemm<<<dim3(36, 12, 3), 256, 0, stream>>>(text_emb, emb, Wq, bq, Wk, bk, Wv, bv, Q, K, V);
    attn<<<dim3(NB), 256, 0, stream>>>(Q, K, V, lw, lb, Ag, ctx);
    recur<<<dim3(1104), 64, 0, stream>>>(Ag, ctx, rec);
}

// Round 16
// 189.277 us; speedup vs baseline: 2.7487x; 1.4357x over previous
//
#include <hip/hip_runtime.h>
#include <math.h>

#define NB 46
#define NS 50
#define ND 768
#define GAMA 0.96875f
#define NM 2300   // NB*NS rows

using bfrag  = __attribute__((ext_vector_type(8))) short;   // 8 bf16 = 4 VGPRs
using f32x16 = __attribute__((ext_vector_type(16))) float;  // 32x32 acc

union FragU { unsigned u[4]; bfrag f; };

// hi/lo bf16 split of 8 f32 (truncation; combined ~16-bit mantissa)
__device__ __forceinline__ void cvt_hilo(const float f[8], bfrag& fh, bfrag& fl)
{
    FragU uh, ul;
    #pragma unroll
    for (int t = 0; t < 4; t++) {
        const unsigned b0 = __float_as_uint(f[2 * t]);
        const unsigned b1 = __float_as_uint(f[2 * t + 1]);
        uh.u[t] = (b0 >> 16) | (b1 & 0xFFFF0000u);
        const float r0 = f[2 * t]     - __uint_as_float(b0 & 0xFFFF0000u);
        const float r1 = f[2 * t + 1] - __uint_as_float(b1 & 0xFFFF0000u);
        ul.u[t] = (__float_as_uint(r0) >> 16) | (__float_as_uint(r1) & 0xFFFF0000u);
    }
    fh = uh.f; fl = ul.f;
}

// ---------------- Kernel 1: QKV projections via MFMA + LDS staging --------
// R15 analysis: R14's MFMA qkv was null vs fp32 because its per-lane loads
// were row-strided (3KB stride -> every 16B request its own cache line,
// ~4-8x L1/L2 overfetch ~ same ~100us as the fp32 VALU bound). Fix: R1's
// coalesced float4 staging into k-major LDS tiles [32][68] (2-way bank
// alias = free), frag reads sweep consecutive banks, then R14's verified
// MFMA fragment + epilogue conventions. 24 iters x (stage + 2x 3-MFMA).
__global__ __launch_bounds__(256) void qkv_gemm(
    const float* __restrict__ text_emb, const float* __restrict__ emb,
    const float* __restrict__ Wq, const float* __restrict__ bq,
    const float* __restrict__ Wk, const float* __restrict__ bk,
    const float* __restrict__ Wv, const float* __restrict__ bv,
    float* __restrict__ Q, float* __restrict__ K, float* __restrict__ V)
{
    const int z = blockIdx.z;
    const float* X    = (z == 0) ? text_emb : emb;
    const float* W    = (z == 0) ? Wq : (z == 1) ? Wk : Wv;
    const float* bias = (z == 0) ? bq : (z == 1) ? bk : bv;
    float* out        = (z == 0) ? Q  : (z == 1) ? K  : V;

    __shared__ float Xs[32][68];
    __shared__ float Ws[32][68];

    const int tid = threadIdx.x;
    const int w   = tid >> 6;           // wave 0..3
    const int l   = tid & 63;
    const int c   = l & 31;
    const int h   = l >> 5;
    const int wm  = w >> 1, wn = w & 1; // quadrant
    const int m0  = blockIdx.x * 64, n0 = blockIdx.y * 64;

    const int lrow = tid >> 2;          // 0..63
    const int lk   = (tid & 3) * 4;     // 0,4,8,12
    const int xm   = m0 + lrow;
    const float* __restrict__ Xrow = X + (size_t)(xm < NM ? xm : 0) * ND;
    const float* __restrict__ Wrow = W + (size_t)(n0 + lrow) * ND;

    f32x16 acc;
    #pragma unroll
    for (int g = 0; g < 16; g++) acc[g] = 0.f;

    for (int k0 = 0; k0 < ND; k0 += 32) {
        // coalesced loads (issued before the barrier; in flight across it)
        const float4 xv0 = *reinterpret_cast<const float4*>(&Xrow[k0 + lk]);
        const float4 xv1 = *reinterpret_cast<const float4*>(&Xrow[k0 + 16 + lk]);
        const float4 wv0 = *reinterpret_cast<const float4*>(&Wrow[k0 + lk]);
        const float4 wv1 = *reinterpret_cast<const float4*>(&Wrow[k0 + 16 + lk]);
        __syncthreads();   // previous iteration's frag reads complete
        Xs[lk + 0][lrow] = xv0.x; Xs[lk + 1][lrow] = xv0.y;
        Xs[lk + 2][lrow] = xv0.z; Xs[lk + 3][lrow] = xv0.w;
        Xs[16 + lk + 0][lrow] = xv1.x; Xs[16 + lk + 1][lrow] = xv1.y;
        Xs[16 + lk + 2][lrow] = xv1.z; Xs[16 + lk + 3][lrow] = xv1.w;
        Ws[lk + 0][lrow] = wv0.x; Ws[lk + 1][lrow] = wv0.y;
        Ws[lk + 2][lrow] = wv0.z; Ws[lk + 3][lrow] = wv0.w;
        Ws[16 + lk + 0][lrow] = wv1.x; Ws[16 + lk + 1][lrow] = wv1.y;
        Ws[16 + lk + 2][lrow] = wv1.z; Ws[16 + lk + 3][lrow] = wv1.w;
        __syncthreads();

        #pragma unroll
        for (int kt = 0; kt < 2; kt++) {
            float fx[8], fw[8];
            #pragma unroll
            for (int j = 0; j < 8; j++) {
                fx[j] = Xs[16 * kt + 8 * h + j][32 * wm + c];
                fw[j] = Ws[16 * kt + 8 * h + j][32 * wn + c];
            }
            bfrag Ah, Al, Bh, Bl;
            cvt_hilo(fx, Ah, Al);
            cvt_hilo(fw, Bh, Bl);
            acc = __builtin_amdgcn_mfma_f32_32x32x16_bf16(Ah, Bh, acc, 0, 0, 0);
            acc = __builtin_amdgcn_mfma_f32_32x32x16_bf16(Ah, Bl, acc, 0, 0, 0);
            acc = __builtin_amdgcn_mfma_f32_32x32x16_bf16(Al, Bh, acc, 0, 0, 0);
        }
    }

    // epilogue: C/D layout col=c, row=(g&3)+8*(g>>2)+4*h (R14, verified)
    const float C2 = -0.0239861701969175f; // -2*ln(10000)/768
    const int n = n0 + 32 * wn + c;
    #pragma unroll
    for (int g = 0; g < 16; g++) {
        const int rr = (g & 3) + 8 * (g >> 2) + 4 * h;
        const int m  = m0 + 32 * wm + rr;
        if (m >= NM) continue;
        float v = acc[g] + bias[n];
        if (z < 2) {
            const int bpos = m / NS;  // pe indexed by BATCH position (faithful)
            const float ang = (float)bpos * expf((float)(n >> 1) * C2);
            v += (n & 1) ? cosf(ang) : sinf(ang);
        }
        out[(size_t)m * ND + n] = v;
    }
}

// ---------------- Kernel 2: attention via MFMA, one block per b ------------
// (R15 version, unchanged.)
__global__ __launch_bounds__(256, 1) void attn(
    const float* __restrict__ Q, const float* __restrict__ K,
    const float* __restrict__ V,
    const float* __restrict__ lin_w, const float* __restrict__ lin_b,
    float* __restrict__ Ag, float* __restrict__ ctx_out)
{
    const int b   = blockIdx.x;
    const int tid = threadIdx.x;
    const int w   = tid >> 6;          // wave 0..3
    const int l   = tid & 63;
    const int c   = l & 31;
    const int h   = l >> 5;

    __shared__ float Lsh[9 * 64 * 68];           // 153 KB
    float* SP = Lsh;                              // 4 partial S tiles
    float* QP = Lsh + 4 * 64 * 68;                // 4 partial Qt tiles
    float* Pf = Lsh + 8 * 64 * 68;                // P

    const float* __restrict__ Qb = Q + (size_t)b * NS * ND;
    const float* __restrict__ Kb = K + (size_t)b * NS * ND;
    const float* __restrict__ Vb = V + (size_t)b * NS * ND;

    f32x16 accS[2][2], accQ[2][2];
    #pragma unroll
    for (int mt = 0; mt < 2; mt++)
        #pragma unroll
        for (int nt = 0; nt < 2; nt++)
            #pragma unroll
            for (int g = 0; g < 16; g++) { accS[mt][nt][g] = 0.f; accQ[mt][nt][g] = 0.f; }

    const int ks = w * 192;
    for (int kt = 0; kt < 12; ++kt) {
        const int ko = ks + kt * 16 + 8 * h;
        bfrag Qh[2], Ql[2], Kh[2], Kl[2], Wh[2], Wl[2];
        #pragma unroll
        for (int mt = 0; mt < 2; mt++) {
            const int row = 32 * mt + c;
            const int r = (row < NS) ? row : 0;
            float f[8];
            {
                const float4 a0 = *reinterpret_cast<const float4*>(&Qb[(size_t)r * ND + ko]);
                const float4 a1 = *reinterpret_cast<const float4*>(&Qb[(size_t)r * ND + ko + 4]);
                f[0]=a0.x; f[1]=a0.y; f[2]=a0.z; f[3]=a0.w; f[4]=a1.x; f[5]=a1.y; f[6]=a1.z; f[7]=a1.w;
            }
            cvt_hilo(f, Qh[mt], Ql[mt]);
            {
                const float4 a0 = *reinterpret_cast<const float4*>(&Kb[(size_t)r * ND + ko]);
                const float4 a1 = *reinterpret_cast<const float4*>(&Kb[(size_t)r * ND + ko + 4]);
                f[0]=a0.x; f[1]=a0.y; f[2]=a0.z; f[3]=a0.w; f[4]=a1.x; f[5]=a1.y; f[6]=a1.z; f[7]=a1.w;
            }
            cvt_hilo(f, Kh[mt], Kl[mt]);
            {
                const float4 a0 = *reinterpret_cast<const float4*>(&lin_w[(size_t)r * ND + ko]);
                const float4 a1 = *reinterpret_cast<const float4*>(&lin_w[(size_t)r * ND + ko + 4]);
                f[0]=a0.x; f[1]=a0.y; f[2]=a0.z; f[3]=a0.w; f[4]=a1.x; f[5]=a1.y; f[6]=a1.z; f[7]=a1.w;
            }
            cvt_hilo(f, Wh[mt], Wl[mt]);
        }
        #pragma unroll
        for (int mt = 0; mt < 2; mt++)
            #pragma unroll
            for (int nt = 0; nt < 2; nt++) {
                f32x16 a = accS[mt][nt];
                a = __builtin_amdgcn_mfma_f32_32x32x16_bf16(Qh[mt], Kh[nt], a, 0, 0, 0);
                a = __builtin_amdgcn_mfma_f32_32x32x16_bf16(Qh[mt], Kl[nt], a, 0, 0, 0);
                a = __builtin_amdgcn_mfma_f32_32x32x16_bf16(Ql[mt], Kh[nt], a, 0, 0, 0);
                accS[mt][nt] = a;
                f32x16 q = accQ[mt][nt];
                q = __builtin_amdgcn_mfma_f32_32x32x16_bf16(Qh[mt], Wh[nt], q, 0, 0, 0);
                q = __builtin_amdgcn_mfma_f32_32x32x16_bf16(Qh[mt], Wl[nt], q, 0, 0, 0);
                q = __builtin_amdgcn_mfma_f32_32x32x16_bf16(Ql[mt], Wh[nt], q, 0, 0, 0);
                accQ[mt][nt] = q;
            }
    }

    {
        float* SPw = SP + w * (64 * 68);
        float* QPw = QP + w * (64 * 68);
        #pragma unroll
        for (int mt = 0; mt < 2; mt++)
            #pragma unroll
            for (int nt = 0; nt < 2; nt++)
                #pragma unroll
                for (int g = 0; g < 16; g++) {
                    const int rg  = 32 * mt + (g & 3) + 8 * (g >> 2) + 4 * h;
                    const int col = 32 * nt + c;
                    SPw[rg * 68 + col] = accS[mt][nt][g];
                    QPw[rg * 68 + col] = accQ[mt][nt][g];
                }
    }
    __syncthreads();

    {
        const int r  = tid >> 2;
        const int cg = (tid & 3) * 16;
        #pragma unroll
        for (int q4 = 0; q4 < 4; ++q4) {
            const int off = r * 68 + cg + q4 * 4;
            float4 s0 = *reinterpret_cast<const float4*>(&SP[off]);
            float4 s1 = *reinterpret_cast<const float4*>(&SP[64 * 68 + off]);
            float4 s2 = *reinterpret_cast<const float4*>(&SP[2 * 64 * 68 + off]);
            float4 s3 = *reinterpret_cast<const float4*>(&SP[3 * 64 * 68 + off]);
            float4 r4;
            r4.x = 8.f * ((s0.x + s1.x) + (s2.x + s3.x));
            r4.y = 8.f * ((s0.y + s1.y) + (s2.y + s3.y));
            r4.z = 8.f * ((s0.z + s1.z) + (s2.z + s3.z));
            r4.w = 8.f * ((s0.w + s1.w) + (s2.w + s3.w));
            *reinterpret_cast<float4*>(&SP[off]) = r4;
            float4 t0 = *reinterpret_cast<const float4*>(&QP[off]);
            float4 t1 = *reinterpret_cast<const float4*>(&QP[64 * 68 + off]);
            float4 t2 = *reinterpret_cast<const float4*>(&QP[2 * 64 * 68 + off]);
            float4 t3 = *reinterpret_cast<const float4*>(&QP[3 * 64 * 68 + off]);
            float4 u4;
            u4.x = (t0.x + t1.x) + (t2.x + t3.x);
            u4.y = (t0.y + t1.y) + (t2.y + t3.y);
            u4.z = (t0.z + t1.z) + (t2.z + t3.z);
            u4.w = (t0.w + t1.w) + (t2.w + t3.w);
            *reinterpret_cast<float4*>(&QP[off]) = u4;
        }
    }
    __syncthreads();

    if (tid < NS) {
        const float* Sr = SP + tid * 68;
        float mx = -INFINITY;
        for (int c2 = 0; c2 < NS; ++c2) mx = fmaxf(mx, Sr[c2]);
        float sum = 0.f;
        for (int c2 = 0; c2 < NS; ++c2) {
            const float e = expf(Sr[c2] - mx);
            Pf[tid * 68 + c2] = e;
            sum += e;
        }
        const float inv = 1.f / sum;
        for (int c2 = 0; c2 < NS; ++c2) Pf[tid * 68 + c2] *= inv;
        for (int c2 = NS; c2 < 64; ++c2) Pf[tid * 68 + c2] = 0.f;
    }
    for (int e = tid; e < NS * NS; e += 256) {
        const int r = e / NS, cc = e - r * NS;
        Ag[b * (NS * NS) + e] = GAMA * (QP[r * 68 + cc] + lin_b[cc]);
    }
    __syncthreads();

    bfrag Ph[2][4], Pl[2][4];
    #pragma unroll
    for (int mt = 0; mt < 2; mt++)
        #pragma unroll
        for (int kt = 0; kt < 4; kt++) {
            float f[8];
            #pragma unroll
            for (int j = 0; j < 8; j++)
                f[j] = Pf[(32 * mt + c) * 68 + kt * 16 + 8 * h + j];
            cvt_hilo(f, Ph[mt][kt], Pl[mt][kt]);
        }

    for (int j3 = 0; j3 < 3; ++j3) {
        const int dbase = (w * 3 + j3) * 64;
        f32x16 accC[2][2];
        #pragma unroll
        for (int mt = 0; mt < 2; mt++)
            #pragma unroll
            for (int nt = 0; nt < 2; nt++)
                #pragma unroll
                for (int g = 0; g < 16; g++) accC[mt][nt][g] = 0.f;

        #pragma unroll
        for (int nt = 0; nt < 2; nt++) {
            const int d = dbase + 32 * nt + c;
            #pragma unroll
            for (int kt = 0; kt < 4; kt++) {
                float f[8];
                #pragma unroll
                for (int j = 0; j < 8; j++) {
                    const int k2 = kt * 16 + 8 * h + j;
                    f[j] = (k2 < NS) ? Vb[(size_t)k2 * ND + d] : 0.f;
                }
                bfrag Bh, Bl;
                cvt_hilo(f, Bh, Bl);
                #pragma unroll
                for (int mt = 0; mt < 2; mt++) {
                    f32x16 a = accC[mt][nt];
                    a = __builtin_amdgcn_mfma_f32_32x32x16_bf16(Ph[mt][kt], Bh, a, 0, 0, 0);
                    a = __builtin_amdgcn_mfma_f32_32x32x16_bf16(Ph[mt][kt], Bl, a, 0, 0, 0);
                    a = __builtin_amdgcn_mfma_f32_32x32x16_bf16(Pl[mt][kt], Bh, a, 0, 0, 0);
                    accC[mt][nt] = a;
                }
            }
        }
        #pragma unroll
        for (int mt = 0; mt < 2; mt++)
            #pragma unroll
            for (int nt = 0; nt < 2; nt++)
                #pragma unroll
                for (int g = 0; g < 16; g++) {
                    const int rg = 32 * mt + (g & 3) + 8 * (g >> 2) + 4 * h;
                    if (rg < NS)
                        ctx_out[((size_t)b * NS + rg) * ND + dbase + 32 * nt + c] = accC[mt][nt][g];
                }
    }
}

// ---------------- Kernel 3: gamma-decay recurrence via MFMA ----------------
// (R13 version, unchanged — fat VMEM through LDS layout-transpose; ~104us.)
__global__ __launch_bounds__(64, 1) void recur(
    const float* __restrict__ Ag, const float* __restrict__ ctx,
    float* __restrict__ rec)
{
    const int blk   = blockIdx.x;          // 0..1103
    const int b     = blk / 24;
    const int chunk = blk - b * 24;        // 0..23 -> 32 cols
    const int l     = threadIdx.x;
    const int c     = l & 31;
    const int h     = l >> 5;
    const int d0    = chunk * 32;
    const int srow  = l >> 3;              // 0..7
    const int scol  = (l & 7) * 4;         // 0,4..28

    __shared__ float Sf[64 * 32];
    __shared__ float Cx[64 * 32];

    const float* __restrict__ Ab = Ag + b * (NS * NS);
    bfrag Ah[2][4], Al[2][4];
    #pragma unroll
    for (int mt = 0; mt < 2; mt++) {
        const int row = 32 * mt + c;
        const bool rok = row < NS;
        const float* __restrict__ Arow = Ab + row * NS;
        #pragma unroll
        for (int kt = 0; kt < 4; kt++) {
            FragU uh, ul;
            #pragma unroll
            for (int t = 0; t < 4; t++) {
                const int k0 = 16 * kt + 8 * h + 2 * t;
                const float e = (rok && k0     < NS) ? Arow[k0]     : 0.f;
                const float o = (rok && k0 + 1 < NS) ? Arow[k0 + 1] : 0.f;
                const unsigned ue = __float_as_uint(e), uo = __float_as_uint(o);
                uh.u[t] = (ue >> 16) | (uo & 0xFFFF0000u);
                const float re = e - __uint_as_float(ue & 0xFFFF0000u);
                const float ro = o - __uint_as_float(uo & 0xFFFF0000u);
                ul.u[t] = (__float_as_uint(re) >> 16) | (__float_as_uint(ro) & 0xFFFF0000u);
            }
            Ah[mt][kt] = uh.f; Al[mt][kt] = ul.f;
        }
    }

    {
        const float4 z = make_float4(0.f, 0.f, 0.f, 0.f);
        *reinterpret_cast<float4*>(&Cx[(48 + srow) * 32 + scol]) = z;
        *reinterpret_cast<float4*>(&Cx[(56 + srow) * 32 + scol]) = z;
        *reinterpret_cast<float4*>(&Sf[(48 + srow) * 32 + scol]) = z;
        *reinterpret_cast<float4*>(&Sf[(56 + srow) * 32 + scol]) = z;
    }

    float4 creg[7];
    #pragma unroll
    for (int it = 0; it < 7; ++it) creg[it] = make_float4(0.f, 0.f, 0.f, 0.f);
    {
        const float* __restrict__ src = ctx + d0;
        #pragma unroll
        for (int it = 0; it < 7; ++it) {
            const int r = it * 8 + srow;
            if (r < NS)
                creg[it] = *reinterpret_cast<const float4*>(&src[(size_t)r * ND + scol]);
        }
        float* __restrict__ r0 = rec + (size_t)b * NS * ND + d0;
        #pragma unroll
        for (int it = 0; it < 7; ++it) {
            const int r = it * 8 + srow;
            if (r < NS) {
                *reinterpret_cast<float4*>(&Sf[r * 32 + scol]) = creg[it];
                *reinterpret_cast<float4*>(&r0[(size_t)r * ND + scol]) = creg[it];
            }
        }
    }
    {
        const float* __restrict__ src = ctx + (size_t)NS * ND + d0;
        #pragma unroll
        for (int it = 0; it < 7; ++it) {
            const int r = it * 8 + srow;
            if (r < NS)
                creg[it] = *reinterpret_cast<const float4*>(&src[(size_t)r * ND + scol]);
        }
    }

    for (int i = 1; i < NB; ++i) {
        #pragma unroll
        for (int it = 0; it < 7; ++it) {
            const int r = it * 8 + srow;
            if (r < NS)
                *reinterpret_cast<float4*>(&Cx[r * 32 + scol]) = creg[it];
        }
        if (i + 1 < NB) {
            const float* __restrict__ src = ctx + (size_t)(i + 1) * NS * ND + d0;
            #pragma unroll
            for (int it = 0; it < 7; ++it) {
                const int r = it * 8 + srow;
                if (r < NS)
                    creg[it] = *reinterpret_cast<const float4*>(&src[(size_t)r * ND + scol]);
            }
        }
        f32x16 acc[2];
        #pragma unroll
        for (int mt = 0; mt < 2; mt++)
            #pragma unroll
            for (int g = 0; g < 16; g++) {
                const int rg = 32 * mt + (g & 3) + 8 * (g >> 2) + 4 * h;
                acc[mt][g] = Cx[rg * 32 + c];
            }
        bfrag Bh[4], Bl[4];
        #pragma unroll
        for (int kt = 0; kt < 4; kt++) {
            float f[8];
            #pragma unroll
            for (int j = 0; j < 8; j++)
                f[j] = Sf[(16 * kt + 8 * h + j) * 32 + c];
            FragU uh, ul;
            #pragma unroll
            for (int t = 0; t < 4; t++) {
                const unsigned b0 = __float_as_uint(f[2 * t]);
                const unsigned b1 = __float_as_uint(f[2 * t + 1]);
                uh.u[t] = (b0 >> 16) | (b1 & 0xFFFF0000u);
                const float r0f = f[2 * t]     - __uint_as_float(b0 & 0xFFFF0000u);
                const float r1f = f[2 * t + 1] - __uint_as_float(b1 & 0xFFFF0000u);
                ul.u[t] = (__float_as_uint(r0f) >> 16) | (__float_as_uint(r1f) & 0xFFFF0000u);
            }
            Bh[kt] = uh.f; Bl[kt] = ul.f;
        }
        #pragma unroll
        for (int mt = 0; mt < 2; mt++) {
            f32x16 a = acc[mt];
            #pragma unroll
            for (int kt = 0; kt < 4; kt++)
                a = __builtin_amdgcn_mfma_f32_32x32x16_bf16(Ah[mt][kt], Bh[kt], a, 0, 0, 0);
            #pragma unroll
            for (int kt = 0; kt < 4; kt++)
                a = __builtin_amdgcn_mfma_f32_32x32x16_bf16(Ah[mt][kt], Bl[kt], a, 0, 0, 0);
            #pragma unroll
            for (int kt = 0; kt < 4; kt++)
                a = __builtin_amdgcn_mfma_f32_32x32x16_bf16(Al[mt][kt], Bh[kt], a, 0, 0, 0);
            acc[mt] = a;
        }
        #pragma unroll
        for (int mt = 0; mt < 2; mt++)
            #pragma unroll
            for (int g = 0; g < 16; g++) {
                const int rg = 32 * mt + (g & 3) + 8 * (g >> 2) + 4 * h;
                Sf[rg * 32 + c] = acc[mt][g];
            }
        float* __restrict__ reci = rec + (size_t)(i * NB + b) * NS * ND + d0;
        #pragma unroll
        for (int it = 0; it < 7; ++it) {
            const int r = it * 8 + srow;
            if (r < NS) {
                const float4 v = *reinterpret_cast<const float4*>(&Sf[r * 32 + scol]);
                *reinterpret_cast<float4*>(&reci[(size_t)r * ND + scol]) = v;
            }
        }
    }
}

extern "C" void kernel_launch(void* const* d_in, const int* in_sizes, int n_in,
                              void* d_out, int out_size, void* d_ws, size_t ws_size,
                              hipStream_t stream) {
    const float* text_emb = (const float*)d_in[0];
    const float* emb      = (const float*)d_in[1];
    const float* Wq = (const float*)d_in[2]; const float* bq = (const float*)d_in[3];
    const float* Wk = (const float*)d_in[4]; const float* bk = (const float*)d_in[5];
    const float* Wv = (const float*)d_in[6]; const float* bv = (const float*)d_in[7];
    const float* lw = (const float*)d_in[8]; const float* lb = (const float*)d_in[9];

    float* out = (float*)d_out;
    float* ctx = out;                          // [46,50,768]
    float* rec = out + NB * NS * ND;           // [46,46,50,768]

    float* ws = (float*)d_ws;                  // needs 21.7 MB
    float* Q  = ws;
    float* K  = Q + NB * NS * ND;
    float* V  = K + NB * NS * ND;
    float* Ag = V + NB * NS * ND;              // gamma * Q_trans, [46,50,50]

    qkv_gemm<<<dim3(36, 12, 3), 256, 0, stream>>>(text_emb, emb, Wq, bq, Wk, bk, Wv, bv, Q, K, V);
    attn<<<dim3(NB), 256, 0, stream>>>(Q, K, V, lw, lb, Ag, ctx);
    recur<<<dim3(1104), 64, 0, stream>>>(Ag, ctx, rec);
}